// Round 4
// baseline (277.150 us; speedup 1.0000x reference)
//
#include <hip/hip_runtime.h>
#include <math.h>

#define Bc 8
#define Tc 60
#define Sc 36
#define Hc_ 4
#define Ec 16
#define PEc 16
#define ADc 12
#define TAc 10
#define OUTc 64
#define KEEP 648
#define EPSc 1e-5f
#define LOG1E4_8 1.15129254649702284f   // ln(10000)/8

// workspace layout (float offsets)
#define WS_H2     18176                    // B*H*S*T*E = 1105920  (layer-1 output, TRANSPOSED [bh][s][t][e])
#define WS_H1     1124096                  // 1105920              (layer-0 output, [bh][t][s][e])
#define WS_ALPHA  2230016                  // B*H*T*S*S = 2488320
#define WS_ADJ    4759808                  // B*H*S*S = 41472
#define WS_ADJP   4801280                  // B*H*S*S = 41472 (pre-prune adj sums, one matrix per bh)
#define WS_CNT    5050112                  // B*S = 288 (mask counts)
#define WS_PE     5050496                  // B*T*PE = 7680 (sinusoidal PE table)
#define WS_DONE1  5058176                  // 32 uint counters (layer01 per-bh)
#define WS_DONE2  5058208                  // 32 uint counters (kF2 per-bh)
// final-chain buffers overlay the (dead-by-then) ALPHA region:
#define WS_BETA   WS_ALPHA                 // B*H*S*T = 69120
#define WS_PART   (WS_ALPHA + 69120)       // B*H*S*2 = 2304
#define WS_OUT2   (WS_ALPHA + 71424)       // B*H*S*16 = 18432
#define WS_PART2  (WS_ALPHA + 89856)       // B*H*S*2 = 2304

// lrelu(v) == max(v, 0.01*v) bitwise for all finite v (2 VALU ops vs 3)
__device__ __forceinline__ float lrelu(float v){ return fmaxf(v, 0.01f*v); }

// ---- kernel 1: BN + embed + layer0 + alpha1; designated blocks: mask counts;
//      per-bh last block: alpha t-sum (exact adjpart+prune order) ----
__global__ __launch_bounds__(256) void k_layer01(const float* __restrict__ x,
                          const float* __restrict__ times,
                          const float* __restrict__ mask,
                          const float* __restrict__ bn_g,
                          const float* __restrict__ bn_b,
                          const float* __restrict__ obs_w,
                          const float* __restrict__ attn,
                          const float* __restrict__ bidw,
                          const float* __restrict__ projW,
                          const float* __restrict__ projb,
                          float* __restrict__ ws){
    int idx = blockIdx.x;                 // (b*H + h)*T + t
    int t = idx % Tc; int bh = idx / Tc; int h = bh % Hc_; int b = bh / Hc_;
    int tid = threadIdx.x;
    __shared__ float sh_h[Sc*Ec];
    __shared__ float sh_h1[Sc*Ec];
    __shared__ float sh_pe[PEc];
    __shared__ float sh_at0T[ADc*Sc];     // [d][j]
    __shared__ float sh_at1T[ADc*Sc];
    __shared__ float sh_bwT[ADc*Sc];
    __shared__ float sh_hp[Sc*28];
    __shared__ float sh_P[Sc];
    __shared__ float sh_w[Sc*Sc];
    __shared__ float sh_xn[Sc];
    __shared__ float sh_m[Sc];
    __shared__ float sred[8];
    __shared__ int sh_last;
    float s0 = 0.f, s1 = 0.f;
    for (int i = tid; i < Bc*Sc; i += 256){
        float v = x[((i/Sc)*Tc + t)*Sc + (i%Sc)];
        s0 += v; s1 += v*v;
    }
    #pragma unroll
    for (int off = 32; off; off >>= 1){
        s0 += __shfl_down(s0, off, 64);
        s1 += __shfl_down(s1, off, 64);
    }
    if ((tid & 63) == 0){ sred[(tid>>6)*2] = s0; sred[(tid>>6)*2 + 1] = s1; }
    if (tid >= 64 && tid < 80){
        int q = tid - 64; int j = q >> 1;
        float ang = times[b*Tc + t] * expf(-(float)j * LOG1E4_8);
        float pv = (q & 1) ? cosf(ang) : sinf(ang);
        sh_pe[q] = pv;
        if (h == 0) ws[WS_PE + (b*Tc + t)*PEc + q] = pv;   // persist PE table
    }
    // mask counts (moved from old adjpart; verbatim loop -> bit-identical)
    if (t == 0 && h == 0 && tid >= 128 && tid < 128 + Sc){
        int ss = tid - 128;
        float c = 0.f;
        #pragma unroll 4
        for (int tt = 0; tt < Tc; tt++) c += mask[(b*Tc + tt)*Sc + ss];
        ws[WS_CNT + b*Sc + ss] = c;
    }
    for (int i = tid; i < ADc*Sc; i += 256){
        int d = i / Sc, j = i % Sc;
        sh_at0T[i] = attn[h*Sc*ADc + j*ADc + d];
        sh_at1T[i] = attn[(Hc_ + h)*Sc*ADc + j*ADc + d];
        sh_bwT[i]  = bidw[h*Sc*ADc + j*ADc + d];
    }
    __syncthreads();
    float mu  = (sred[0]+sred[2]+sred[4]+sred[6]) / (float)(Bc*Sc);
    float var = (sred[1]+sred[3]+sred[5]+sred[7]) / (float)(Bc*Sc) - mu*mu;
    if (tid < Sc){
        float xv = x[(b*Tc + t)*Sc + tid];
        sh_xn[tid] = (xv - mu) * rsqrtf(var + EPSc) * bn_g[t] + bn_b[t];
        sh_m[tid]  = mask[(b*Tc + t)*Sc + tid];
    }
    __syncthreads();
    for (int i = tid; i < Sc*Ec; i += 256){
        int s = i / Ec, e = i % Ec;
        sh_h[i] = lrelu(sh_xn[s]*obs_w[s*64 + h*Ec + e]) * sh_m[s];
    }
    __syncthreads();
    for (int i = tid; i < Sc*28; i += 256){
        int s = i / 28, d = i % 28;
        float acc = projb[d];
        const float* w = projW + d*Ec;
        const float* hh = sh_h + s*Ec;
        #pragma unroll
        for (int e = 0; e < Ec; e++) acc += hh[e]*w[e];
        sh_hp[i] = acc;
    }
    __syncthreads();
    if (tid < Sc){
        const float* hp = sh_hp + tid*28 + ADc;
        float p = 0.f;
        #pragma unroll
        for (int d = 0; d < PEc; d++) p += hp[d]*sh_pe[d];
        sh_P[tid] = p;
    }
    __syncthreads();
    for (int i = tid; i < Sc*Sc; i += 256){
        int s = i / Sc, j = i % Sc;
        const float* hp = sh_hp + s*28;
        float acc = sh_P[s];
        float bd = 0.f;
        #pragma unroll
        for (int d = 0; d < ADc; d++){
            acc += hp[d]*sh_at0T[d*Sc + j];
            bd  += sh_bwT[d*Sc + s]*sh_bwT[d*Sc + j];
        }
        sh_w[i] = lrelu(lrelu(bd)*lrelu(acc));
    }
    __syncthreads();
    float* h1g = ws + WS_H1 + (size_t)idx*Sc*Ec;
    for (int i = tid; i < Sc*Ec; i += 256){
        int s = i / Ec, e = i % Ec;
        float acc = 0.f;
        #pragma unroll 6
        for (int j = 0; j < Sc; j++) acc += lrelu(sh_h[j*Ec + e]*sh_w[s*Sc + j]);
        float v = lrelu(acc);
        sh_h1[i] = v;
        h1g[i] = v;
    }
    __syncthreads();
    for (int i = tid; i < Sc*28; i += 256){
        int s = i / 28, d = i % 28;
        float acc = projb[d];
        const float* w = projW + d*Ec;
        const float* hh = sh_h1 + s*Ec;
        #pragma unroll
        for (int e = 0; e < Ec; e++) acc += hh[e]*w[e];
        sh_hp[i] = acc;
    }
    __syncthreads();
    if (tid < Sc){
        const float* hp = sh_hp + tid*28 + ADc;
        float p = 0.f;
        #pragma unroll
        for (int d = 0; d < PEc; d++) p += hp[d]*sh_pe[d];
        sh_P[tid] = p;
    }
    __syncthreads();
    float* adst = ws + WS_ALPHA + (size_t)idx*Sc*Sc;
    for (int i = tid; i < Sc*Sc; i += 256){
        int s = i / Sc, j = i % Sc;
        const float* hp = sh_hp + s*28;
        float acc = sh_P[s];
        #pragma unroll
        for (int d = 0; d < ADc; d++) acc += hp[d]*sh_at1T[d*Sc + j];
        adst[i] = lrelu(acc);
    }
    // ---- per-bh last block: alpha t-sum into WS_ADJP (replaces k_adjpart) ----
    __syncthreads();
    if (tid == 0){
        __threadfence();   // release: publish this block's alpha writes
        unsigned old = atomicAdd((unsigned*)(ws + WS_DONE1) + bh, 1u);
        sh_last = (old == Tc - 1);
    }
    __syncthreads();
    if (sh_last){
        if (tid == 0) __threadfence();   // acquire: see siblings' alpha writes
        __syncthreads();
        const float4* a = (const float4*)(ws + WS_ALPHA + (size_t)bh*Tc*Sc*Sc);
        float4* p = (float4*)(ws + WS_ADJP + (size_t)bh*Sc*Sc);
        for (int c = tid; c < 324; c += 256){
            float4 acc = make_float4(0.f, 0.f, 0.f, 0.f);
            #pragma unroll
            for (int q = 0; q < 6; q++){
                // exact old adjpart chunk partial (tt ascending, acc from 0)
                float4 pq = make_float4(0.f, 0.f, 0.f, 0.f);
                #pragma unroll
                for (int tt = 0; tt < 10; tt++){
                    float4 u = a[(size_t)(q*10 + tt)*324 + c];
                    pq.x += u.x; pq.y += u.y; pq.z += u.z; pq.w += u.w;
                }
                // exact old prune chunk accumulation order
                acc.x += pq.x; acc.y += pq.y; acc.z += pq.z; acc.w += pq.w;
            }
            p[c] = acc;
        }
    }
}

// ---- kernel 2: stable-rank prune (768 blocks); reads pre-summed WS_ADJP ----
__global__ __launch_bounds__(256) void k_prune(float* __restrict__ ws){
    int bh = blockIdx.x / 24; int chunk = blockIdx.x % 24;
    int b = bh >> 2;
    int tid = threadIdx.x;
    __shared__ __align__(16) float sh_v[Sc*Sc];
    __shared__ float sh_cnt[Sc];
    const float4* p = (const float4*)(ws + WS_ADJP + (size_t)bh*Sc*Sc);
    for (int c = tid; c < 324; c += 256) ((float4*)sh_v)[c] = p[c];
    if (tid < Sc) sh_cnt[tid] = ws[WS_CNT + b*Sc + tid];
    __syncthreads();
    for (int i = tid; i < Sc*Sc; i += 256){
        int s = i / Sc;
        sh_v[i] = lrelu(sh_v[i] / sh_cnt[s]);
    }
    __syncthreads();
    int r = tid >> 2; if (r > 53) r = 53;
    int part = tid & 3;
    int i = chunk*54 + r;
    float v = sh_v[i];
    const float4* v4 = (const float4*)sh_v + part*81;
    int a0 = part*324;
    int cnt = 0;
    #pragma unroll 9
    for (int j = 0; j < 81; j++){
        float4 u = v4[j];
        int k = a0 + j*4;
        cnt += (int)(u.x < v) + ((int)(u.x == v) & (int)(k   < i));
        cnt += (int)(u.y < v) + ((int)(u.y == v) & (int)(k+1 < i));
        cnt += (int)(u.z < v) + ((int)(u.z == v) & (int)(k+2 < i));
        cnt += (int)(u.w < v) + ((int)(u.w == v) & (int)(k+3 < i));
    }
    cnt += __shfl_down(cnt, 2, 4);
    cnt += __shfl_down(cnt, 1, 4);
    if (part == 0 && tid < 216)
        ws[WS_ADJ + bh*Sc*Sc + i] = (cnt >= KEEP) ? v : 0.f;
}

// ---- kernel 3: layer-1 message passing (h2 TRANSPOSED); block 1920: pair_sim + zero DONE2 ----
__global__ __launch_bounds__(256) void k_layer1mp(const float* __restrict__ bidw,
                                                  float* __restrict__ ws,
                                                  float* __restrict__ out){
    int tid = threadIdx.x;
    __shared__ float sh_h[Sc*Ec];
    __shared__ float sh_w[Sc*Sc];
    __shared__ float sh_bwT[ADc*Sc];      // [d][s]
    if (blockIdx.x == Bc*Hc_*Tc){
        // pair_sim over WS_ADJ (verbatim from old kF3s block 32) + zero kF2 counters
        if (tid < 32) ((int*)(ws + WS_DONE2))[tid] = 0;
        float sq = 0.f, t2 = 0.f;
        for (int i = tid; i < Hc_*Sc*Sc; i += 256){
            float tot = 0.f;
            #pragma unroll
            for (int b = 0; b < Bc; b++){
                float v = ws[WS_ADJ + b*Hc_*Sc*Sc + i];
                sq += v*v; tot += v;
            }
            t2 += tot*tot;
        }
        float* r0 = sh_w; float* r1 = sh_w + 256;   // reuse LDS
        r0[tid] = sq; r1[tid] = t2; __syncthreads();
        for (int off = 128; off; off >>= 1){
            if (tid < off){ r0[tid] += r0[tid+off]; r1[tid] += r1[tid+off]; }
            __syncthreads();
        }
        if (tid == 0)
            out[Bc*Sc*OUTc] = ((float)Bc*r0[0] - r1[0]) / 49.f / 1296.f;
        return;
    }
    int idx = blockIdx.x;
    int t = idx % Tc; int bh = idx / Tc; int h = bh % Hc_;
    const float* hsrc = ws + WS_H1 + (size_t)idx*Sc*Ec;
    const float* al  = ws + WS_ALPHA + (size_t)idx*Sc*Sc;
    const float* adj = ws + WS_ADJ + bh*Sc*Sc;
    for (int i = tid; i < Sc*Ec; i += 256) sh_h[i] = hsrc[i];
    for (int i = tid; i < ADc*Sc; i += 256){
        int d = i / Sc, j = i % Sc;
        sh_bwT[i] = bidw[(Hc_ + h)*Sc*ADc + j*ADc + d];
    }
    __syncthreads();
    for (int i = tid; i < Sc*Sc; i += 256){
        int s = i / Sc, j = i % Sc;
        float bd = 0.f;
        #pragma unroll
        for (int d = 0; d < ADc; d++) bd += sh_bwT[d*Sc + s]*sh_bwT[d*Sc + j];
        sh_w[i] = lrelu(lrelu(bd)*al[i]*adj[i]);
    }
    __syncthreads();
    for (int i = tid; i < Sc*Ec; i += 256){
        int s = i / Ec, e = i % Ec;
        float acc = 0.f;
        #pragma unroll 6
        for (int j = 0; j < Sc; j++) acc += lrelu(sh_h[j*Ec + e]*sh_w[s*Sc + j]);
        // transposed write: [bh][s][t][e]
        ws[WS_H2 + ((size_t)(bh*Sc + s)*Tc + t)*Ec + e] = lrelu(acc);
    }
}

// ------- kernel 4: per-(bh,s) temporal attention: beta + LN1 partials -------
__global__ __launch_bounds__(64) void kF1(const float* __restrict__ Wq, const float* __restrict__ bq,
                   const float* __restrict__ Wk, const float* __restrict__ bk,
                   const float* __restrict__ Ws_, const float* __restrict__ bs_,
                   float* __restrict__ ws){
    int idx = blockIdx.x;                  // bh*Sc + s
    int bh = idx / Sc; int b = bh / Hc_;
    int tid = threadIdx.x;
    __shared__ float sh_Hc[Tc*33];         // row-pad 33
    __shared__ float sh_K[Tc*11];
    __shared__ float sh_Wq[TAc*32];
    __shared__ float sh_WkT[32*TAc];       // [q][d]
    __shared__ float sh_bq[TAc], sh_bk[TAc];
    __shared__ float sh_ws[Tc];
    __shared__ float sh_Kw[TAc];
    const float* h2c = ws + WS_H2 + (size_t)idx*Tc*Ec;   // contiguous [t][e]
    for (int i4 = tid; i4 < Tc*4; i4 += 64){
        int t = i4 >> 2, c4 = i4 & 3;
        float4 u = *(const float4*)(h2c + i4*4);
        float* d = sh_Hc + t*33 + c4*4;
        d[0] = u.x; d[1] = u.y; d[2] = u.z; d[3] = u.w;
    }
    for (int i4 = tid; i4 < Tc*4; i4 += 64){   // PE from table
        int t = i4 >> 2, c4 = i4 & 3;
        float4 u = *(const float4*)(ws + WS_PE + (size_t)(b*Tc + t)*PEc + c4*4);
        float* d = sh_Hc + t*33 + Ec + c4*4;
        d[0] = u.x; d[1] = u.y; d[2] = u.z; d[3] = u.w;
    }
    for (int i = tid; i < TAc*32; i += 64){
        sh_Wq[i] = Wq[i];
        int d = i / 32, q = i % 32;
        sh_WkT[q*TAc + d] = Wk[i];
    }
    if (tid < TAc){ sh_bq[tid] = bq[tid]; sh_bk[tid] = bk[tid]; }
    if (tid < Tc) sh_ws[tid] = Ws_[tid];
    __syncthreads();
    for (int i = tid; i < Tc*TAc; i += 64){
        int t = i / TAc, d = i % TAc;
        const float* hc = sh_Hc + t*33;
        float acc = sh_bk[d];
        #pragma unroll
        for (int q = 0; q < 32; q++) acc += hc[q]*sh_WkT[q*TAc + d];
        sh_K[t*11 + d] = acc;
    }
    __syncthreads();
    if (tid < TAc){
        float acc = 0.f;
        #pragma unroll 4
        for (int t = 0; t < Tc; t++) acc += sh_K[t*11 + tid]*sh_ws[t];
        sh_Kw[tid] = acc;
    }
    __syncthreads();
    float bv = 0.f;
    float bsv = bs_[0];
    if (tid < Tc){
        const float* hc = sh_Hc + tid*33;
        float acc = bsv;
        #pragma unroll
        for (int d = 0; d < TAc; d++){
            const float* wq = sh_Wq + d*32;
            float qv = sh_bq[d];
            #pragma unroll
            for (int q = 0; q < 32; q++) qv += hc[q]*wq[q];
            acc += qv*sh_Kw[d];
        }
        bv = acc;
        ws[WS_BETA + idx*Tc + tid] = acc;
    }
    float p0 = (tid < Tc) ? bv : 0.f;
    float p1 = p0*bv;
    #pragma unroll
    for (int off = 32; off; off >>= 1){
        p0 += __shfl_down(p0, off, 64);
        p1 += __shfl_down(p1, off, 64);
    }
    if (tid == 0){
        ws[WS_PART + idx*2]     = p0;
        ws[WS_PART + idx*2 + 1] = p1;
    }
}

// ------- kernel 5: per-(bh,s) LN1 + out1 + out2 + LN2 partials; per-bh last block: LN2 + final write -------
__global__ __launch_bounds__(64) void kF2(const float* __restrict__ lnt_g, const float* __restrict__ lnt_b,
                   const float* __restrict__ Wse, const float* __restrict__ bse,
                   const float* __restrict__ lns_g, const float* __restrict__ lns_b,
                   float* __restrict__ ws, float* __restrict__ out){
    int idx = blockIdx.x;
    int s = idx % Sc; int bh = idx / Sc; int b = bh / Hc_; int h = bh % Hc_;
    int tid = threadIdx.x;
    __shared__ float sh_Hc[Tc*33];
    __shared__ float sh_beta[Tc];
    __shared__ float sh_o1[32];
    __shared__ float sh_mi[2];
    __shared__ int sh_last;
    float p0 = 0.f, p1 = 0.f;
    if (tid < Sc){
        p0 = ws[WS_PART + (bh*Sc + tid)*2];
        p1 = ws[WS_PART + (bh*Sc + tid)*2 + 1];
    }
    #pragma unroll
    for (int off = 32; off; off >>= 1){
        p0 += __shfl_down(p0, off, 64);
        p1 += __shfl_down(p1, off, 64);
    }
    if (tid == 0){
        float m = p0 / (float)(Sc*Tc);
        sh_mi[0] = m;
        sh_mi[1] = rsqrtf(p1 / (float)(Sc*Tc) - m*m + EPSc);
    }
    const float* h2c = ws + WS_H2 + (size_t)idx*Tc*Ec;   // contiguous [t][e]
    for (int i4 = tid; i4 < Tc*4; i4 += 64){
        int t = i4 >> 2, c4 = i4 & 3;
        float4 u = *(const float4*)(h2c + i4*4);
        float* d = sh_Hc + t*33 + c4*4;
        d[0] = u.x; d[1] = u.y; d[2] = u.z; d[3] = u.w;
    }
    for (int i4 = tid; i4 < Tc*4; i4 += 64){   // PE from table
        int t = i4 >> 2, c4 = i4 & 3;
        float4 u = *(const float4*)(ws + WS_PE + (size_t)(b*Tc + t)*PEc + c4*4);
        float* d = sh_Hc + t*33 + Ec + c4*4;
        d[0] = u.x; d[1] = u.y; d[2] = u.z; d[3] = u.w;
    }
    __syncthreads();
    float m = sh_mi[0], inv = sh_mi[1];
    if (tid < Tc){
        float bvv = ws[WS_BETA + idx*Tc + tid];
        sh_beta[tid] = (bvv - m)*inv*lnt_g[s*Tc + tid] + lnt_b[s*Tc + tid];
    }
    __syncthreads();
    if (tid < 32){
        float acc = 0.f;
        #pragma unroll 4
        for (int t = 0; t < Tc; t++) acc += sh_beta[t]*sh_Hc[t*33 + tid];
        sh_o1[tid] = lrelu(acc);
    }
    __syncthreads();
    float v = 0.f;
    if (tid < 16){
        float acc = bse[tid];
        const float* w = Wse + tid*32;
        #pragma unroll
        for (int d = 0; d < 32; d++) acc += sh_o1[d]*w[d];
        v = lrelu(acc);
        ws[WS_OUT2 + idx*16 + tid] = v;
    }
    float q0 = v, q1 = v*v;
    #pragma unroll
    for (int off = 32; off; off >>= 1){
        q0 += __shfl_down(q0, off, 64);
        q1 += __shfl_down(q1, off, 64);
    }
    if (tid == 0){
        ws[WS_PART2 + idx*2]     = q0;
        ws[WS_PART2 + idx*2 + 1] = q1;
    }
    // ---- per-bh last block: LN2 + final write (replaces kF3s blocks 0..31) ----
    if (tid == 0){
        __threadfence();   // release: publish OUT2/PART2 (single wave: covers all lanes' stores)
        unsigned old = atomicAdd((unsigned*)(ws + WS_DONE2) + bh, 1u);
        sh_last = (old == Sc - 1);
    }
    __syncthreads();
    if (sh_last){
        if (tid == 0) __threadfence();   // acquire
        __syncthreads();
        // verbatim kF3s reduction (tid<64 path; 64-thread block -> identical)
        float r0 = 0.f, r1 = 0.f;
        if (tid < Sc){
            r0 = ws[WS_PART2 + (bh*Sc + tid)*2];
            r1 = ws[WS_PART2 + (bh*Sc + tid)*2 + 1];
        }
        #pragma unroll
        for (int off = 32; off; off >>= 1){
            r0 += __shfl_down(r0, off, 64);
            r1 += __shfl_down(r1, off, 64);
        }
        if (tid == 0){
            float mm = r0 / (float)(Sc*16);
            sh_mi[0] = mm;
            sh_mi[1] = rsqrtf(r1 / (float)(Sc*16) - mm*mm + EPSc);
        }
        __syncthreads();
        float m2 = sh_mi[0], inv2 = sh_mi[1];
        for (int i = tid; i < Sc*16; i += 64){
            int ss = i / 16, k = i % 16;
            float vv = ws[WS_OUT2 + bh*Sc*16 + i];
            out[(b*Sc + ss)*OUTc + h*16 + k] = (vv - m2)*inv2*lns_g[i] + lns_b[i];
        }
    }
}

extern "C" void kernel_launch(void* const* d_in, const int* in_sizes, int n_in,
                              void* d_out, int out_size, void* d_ws, size_t ws_size,
                              hipStream_t stream){
    const float* x     = (const float*)d_in[0];
    const float* times = (const float*)d_in[1];
    const float* mask  = (const float*)d_in[2];
    const float* bn_g  = (const float*)d_in[3];
    const float* bn_b  = (const float*)d_in[4];
    const float* obs   = (const float*)d_in[5];
    const float* attn  = (const float*)d_in[6];
    const float* bidw  = (const float*)d_in[7];
    const float* projW = (const float*)d_in[8];
    const float* projb = (const float*)d_in[9];
    const float* Wq    = (const float*)d_in[10];
    const float* bq    = (const float*)d_in[11];
    const float* Wk    = (const float*)d_in[12];
    const float* bk    = (const float*)d_in[13];
    const float* Ws_   = (const float*)d_in[14];
    const float* bs_   = (const float*)d_in[15];
    const float* lnt_g = (const float*)d_in[16];
    const float* lnt_b = (const float*)d_in[17];
    const float* Wse   = (const float*)d_in[18];
    const float* bse   = (const float*)d_in[19];
    const float* lns_g = (const float*)d_in[20];
    const float* lns_b = (const float*)d_in[21];
    float* ws  = (float*)d_ws;
    float* out = (float*)d_out;

    // zero the layer01 per-bh completion counters (tiny, capture-safe)
    hipMemsetAsync(ws + WS_DONE1, 0, 32*sizeof(unsigned), stream);

    k_layer01<<<Bc*Hc_*Tc, 256, 0, stream>>>(x, times, mask, bn_g, bn_b, obs, attn, bidw, projW, projb, ws);
    k_prune<<<Bc*Hc_*24, 256, 0, stream>>>(ws);
    k_layer1mp<<<Bc*Hc_*Tc + 1, 256, 0, stream>>>(bidw, ws, out);
    kF1<<<Bc*Hc_*Sc, 64, 0, stream>>>(Wq, bq, Wk, bk, Ws_, bs_, ws);
    kF2<<<Bc*Hc_*Sc, 64, 0, stream>>>(lnt_g, lnt_b, Wse, bse, lns_g, lns_b, ws, out);
}

// Round 5
// 191.087 us; speedup vs baseline: 1.4504x; 1.4504x over previous
//
#include <hip/hip_runtime.h>
#include <math.h>

#define Bc 8
#define Tc 60
#define Sc 36
#define Hc_ 4
#define Ec 16
#define PEc 16
#define ADc 12
#define TAc 10
#define OUTc 64
#define KEEP 648
#define EPSc 1e-5f
#define LOG1E4_8 1.15129254649702284f   // ln(10000)/8

// workspace layout (float offsets)
#define WS_H2     18176                    // B*H*S*T*E = 1105920  (layer-1 output, TRANSPOSED [bh][s][t][e])
#define WS_H1     1124096                  // 1105920              (layer-0 output, [bh][t][s][e])
#define WS_ALPHA  2230016                  // B*H*T*S*S = 2488320
#define WS_ADJ    4759808                  // B*H*S*S = 41472
#define WS_ADJP   4801280                  // B*H*6*S*S = 248832 (t-chunk partial sums)
#define WS_CNT    5050112                  // B*S = 288 (mask counts)
#define WS_PE     5050496                  // B*T*PE = 7680 (sinusoidal PE table)
#define WS_BID1   5058176                  // H*S*S = 5184 (lrelu'd layer-1 bidir Gram, per h)
// final-chain buffers overlay the (dead-by-then) ALPHA region:
#define WS_BETA   WS_ALPHA                 // B*H*S*T = 69120
#define WS_PART   (WS_ALPHA + 69120)       // B*H*S*2 = 2304
#define WS_OUT2   (WS_ALPHA + 71424)       // B*H*S*16 = 18432
#define WS_PART2  (WS_ALPHA + 89856)       // B*H*S*2 = 2304

// lrelu(v) == max(v, 0.01*v) bitwise for all finite v (2 VALU ops vs 3)
__device__ __forceinline__ float lrelu(float v){ return fmaxf(v, 0.01f*v); }

// ---- kernel 1: BN(stats+apply) + embed + layer0 (alpha0,w0,mp -> h1) + alpha1 ----
// (proven round-3 version, byte-identical)
__global__ __launch_bounds__(256) void k_layer01(const float* __restrict__ x,
                          const float* __restrict__ times,
                          const float* __restrict__ mask,
                          const float* __restrict__ bn_g,
                          const float* __restrict__ bn_b,
                          const float* __restrict__ obs_w,
                          const float* __restrict__ attn,
                          const float* __restrict__ bidw,
                          const float* __restrict__ projW,
                          const float* __restrict__ projb,
                          float* __restrict__ ws){
    int idx = blockIdx.x;                 // (b*H + h)*T + t
    int t = idx % Tc; int bh = idx / Tc; int h = bh % Hc_; int b = bh / Hc_;
    int tid = threadIdx.x;
    __shared__ float sh_h[Sc*Ec];
    __shared__ float sh_h1[Sc*Ec];
    __shared__ float sh_pe[PEc];
    __shared__ float sh_at0T[ADc*Sc];     // [d][j]
    __shared__ float sh_at1T[ADc*Sc];
    __shared__ float sh_bwT[ADc*Sc];
    __shared__ float sh_hp[Sc*28];
    __shared__ float sh_P[Sc];
    __shared__ float sh_w[Sc*Sc];
    __shared__ float sh_xn[Sc];
    __shared__ float sh_m[Sc];
    __shared__ float sred[8];
    float s0 = 0.f, s1 = 0.f;
    for (int i = tid; i < Bc*Sc; i += 256){
        float v = x[((i/Sc)*Tc + t)*Sc + (i%Sc)];
        s0 += v; s1 += v*v;
    }
    #pragma unroll
    for (int off = 32; off; off >>= 1){
        s0 += __shfl_down(s0, off, 64);
        s1 += __shfl_down(s1, off, 64);
    }
    if ((tid & 63) == 0){ sred[(tid>>6)*2] = s0; sred[(tid>>6)*2 + 1] = s1; }
    if (tid >= 64 && tid < 80){
        int q = tid - 64; int j = q >> 1;
        float ang = times[b*Tc + t] * expf(-(float)j * LOG1E4_8);
        float pv = (q & 1) ? cosf(ang) : sinf(ang);
        sh_pe[q] = pv;
        if (h == 0) ws[WS_PE + (b*Tc + t)*PEc + q] = pv;   // persist PE table
    }
    for (int i = tid; i < ADc*Sc; i += 256){
        int d = i / Sc, j = i % Sc;
        sh_at0T[i] = attn[h*Sc*ADc + j*ADc + d];
        sh_at1T[i] = attn[(Hc_ + h)*Sc*ADc + j*ADc + d];
        sh_bwT[i]  = bidw[h*Sc*ADc + j*ADc + d];
    }
    __syncthreads();
    float mu  = (sred[0]+sred[2]+sred[4]+sred[6]) / (float)(Bc*Sc);
    float var = (sred[1]+sred[3]+sred[5]+sred[7]) / (float)(Bc*Sc) - mu*mu;
    if (tid < Sc){
        float xv = x[(b*Tc + t)*Sc + tid];
        sh_xn[tid] = (xv - mu) * rsqrtf(var + EPSc) * bn_g[t] + bn_b[t];
        sh_m[tid]  = mask[(b*Tc + t)*Sc + tid];
    }
    __syncthreads();
    for (int i = tid; i < Sc*Ec; i += 256){
        int s = i / Ec, e = i % Ec;
        sh_h[i] = lrelu(sh_xn[s]*obs_w[s*64 + h*Ec + e]) * sh_m[s];
    }
    __syncthreads();
    for (int i = tid; i < Sc*28; i += 256){
        int s = i / 28, d = i % 28;
        float acc = projb[d];
        const float* w = projW + d*Ec;
        const float* hh = sh_h + s*Ec;
        #pragma unroll
        for (int e = 0; e < Ec; e++) acc += hh[e]*w[e];
        sh_hp[i] = acc;
    }
    __syncthreads();
    if (tid < Sc){
        const float* hp = sh_hp + tid*28 + ADc;
        float p = 0.f;
        #pragma unroll
        for (int d = 0; d < PEc; d++) p += hp[d]*sh_pe[d];
        sh_P[tid] = p;
    }
    __syncthreads();
    for (int i = tid; i < Sc*Sc; i += 256){
        int s = i / Sc, j = i % Sc;
        const float* hp = sh_hp + s*28;
        float acc = sh_P[s];
        float bd = 0.f;
        #pragma unroll
        for (int d = 0; d < ADc; d++){
            acc += hp[d]*sh_at0T[d*Sc + j];
            bd  += sh_bwT[d*Sc + s]*sh_bwT[d*Sc + j];
        }
        sh_w[i] = lrelu(lrelu(bd)*lrelu(acc));
    }
    __syncthreads();
    float* h1g = ws + WS_H1 + (size_t)idx*Sc*Ec;
    for (int i = tid; i < Sc*Ec; i += 256){
        int s = i / Ec, e = i % Ec;
        float acc = 0.f;
        #pragma unroll 6
        for (int j = 0; j < Sc; j++) acc += lrelu(sh_h[j*Ec + e]*sh_w[s*Sc + j]);
        float v = lrelu(acc);
        sh_h1[i] = v;
        h1g[i] = v;
    }
    __syncthreads();
    for (int i = tid; i < Sc*28; i += 256){
        int s = i / 28, d = i % 28;
        float acc = projb[d];
        const float* w = projW + d*Ec;
        const float* hh = sh_h1 + s*Ec;
        #pragma unroll
        for (int e = 0; e < Ec; e++) acc += hh[e]*w[e];
        sh_hp[i] = acc;
    }
    __syncthreads();
    if (tid < Sc){
        const float* hp = sh_hp + tid*28 + ADc;
        float p = 0.f;
        #pragma unroll
        for (int d = 0; d < PEc; d++) p += hp[d]*sh_pe[d];
        sh_P[tid] = p;
    }
    __syncthreads();
    float* adst = ws + WS_ALPHA + (size_t)idx*Sc*Sc;
    for (int i = tid; i < Sc*Sc; i += 256){
        int s = i / Sc, j = i % Sc;
        const float* hp = sh_hp + s*28;
        float acc = sh_P[s];
        #pragma unroll
        for (int d = 0; d < ADc; d++) acc += hp[d]*sh_at1T[d*Sc + j];
        adst[i] = lrelu(acc);
    }
}

// ---- kernel 2a: per-(bh, t-chunk) partial t-sum of alpha; mask counts;
//      4 designated blocks also hoist the layer-1 bidir Gram (per h, L2-hot) ----
__global__ __launch_bounds__(256) void k_adjpart(const float* __restrict__ mask,
                                                 const float* __restrict__ bidw,
                                                 float* __restrict__ ws){
    int bh = blockIdx.x / 6; int chunk = blockIdx.x % 6;
    int tid = threadIdx.x;
    const float4* a = (const float4*)(ws + WS_ALPHA + (size_t)bh*Tc*Sc*Sc) + (size_t)chunk*10*324;
    float4* p = (float4*)(ws + WS_ADJP + (size_t)blockIdx.x*Sc*Sc);
    for (int c = tid; c < 324; c += 256){
        float4 acc = make_float4(0.f, 0.f, 0.f, 0.f);
        #pragma unroll
        for (int tt = 0; tt < 10; tt++){
            float4 u = a[(size_t)tt*324 + c];
            acc.x += u.x; acc.y += u.y; acc.z += u.z; acc.w += u.w;
        }
        p[c] = acc;
    }
    if (chunk == 0 && (bh & 3) == 0 && tid < Sc){
        int b = bh >> 2;
        float c = 0.f;
        #pragma unroll 4
        for (int t = 0; t < Tc; t++) c += mask[(b*Tc + t)*Sc + tid];
        ws[WS_CNT + b*Sc + tid] = c;
    }
    // layer-1 bidir Gram: only 4 distinct matrices (h); d-ascending sum == old
    // k_layer1mp order -> bit-identical. Blocks (chunk==5, bh<4) do it.
    if (chunk == 5 && bh < Hc_){
        int h = bh;
        const float* bw = bidw + (Hc_ + h)*Sc*ADc;
        for (int i = tid; i < Sc*Sc; i += 256){
            int s = i / Sc, j = i % Sc;
            float bd = 0.f;
            #pragma unroll
            for (int d = 0; d < ADc; d++) bd += bw[s*ADc + d]*bw[j*ADc + d];
            ws[WS_BID1 + h*Sc*Sc + i] = lrelu(bd);
        }
    }
}

// ---- kernel 2b: stable-rank prune, 4-way split scan (768 blocks) ----
__global__ __launch_bounds__(256) void k_prune(float* __restrict__ ws){
    int bh = blockIdx.x / 24; int chunk = blockIdx.x % 24;
    int b = bh >> 2;
    int tid = threadIdx.x;
    __shared__ __align__(16) float sh_v[Sc*Sc];
    __shared__ float sh_cnt[Sc];
    const float4* p = (const float4*)(ws + WS_ADJP + (size_t)bh*6*Sc*Sc);
    for (int c = tid; c < 324; c += 256){
        float4 acc = make_float4(0.f, 0.f, 0.f, 0.f);
        #pragma unroll
        for (int q = 0; q < 6; q++){
            float4 u = p[(size_t)q*324 + c];
            acc.x += u.x; acc.y += u.y; acc.z += u.z; acc.w += u.w;
        }
        ((float4*)sh_v)[c] = acc;
    }
    if (tid < Sc) sh_cnt[tid] = ws[WS_CNT + b*Sc + tid];
    __syncthreads();
    for (int i = tid; i < Sc*Sc; i += 256){
        int s = i / Sc;
        sh_v[i] = lrelu(sh_v[i] / sh_cnt[s]);
    }
    __syncthreads();
    int r = tid >> 2; if (r > 53) r = 53;
    int part = tid & 3;
    int i = chunk*54 + r;
    float v = sh_v[i];
    const float4* v4 = (const float4*)sh_v + part*81;
    int a0 = part*324;
    int cnt = 0;
    #pragma unroll 9
    for (int j = 0; j < 81; j++){
        float4 u = v4[j];
        int k = a0 + j*4;
        cnt += (int)(u.x < v) + ((int)(u.x == v) & (int)(k   < i));
        cnt += (int)(u.y < v) + ((int)(u.y == v) & (int)(k+1 < i));
        cnt += (int)(u.z < v) + ((int)(u.z == v) & (int)(k+2 < i));
        cnt += (int)(u.w < v) + ((int)(u.w == v) & (int)(k+3 < i));
    }
    cnt += __shfl_down(cnt, 2, 4);
    cnt += __shfl_down(cnt, 1, 4);
    if (part == 0 && tid < 216)
        ws[WS_ADJ + bh*Sc*Sc + i] = (cnt >= KEEP) ? v : 0.f;
}

// ---------------- kernel 3: layer 1 message passing (h2 written TRANSPOSED) ----------------
// Gram hoisted: w-loop reads the precomputed lrelu'd Gram from global (L2-hot);
// drops the bwT stage, the 12-MAC Gram loop, and one barrier.
__global__ __launch_bounds__(256) void k_layer1mp(float* __restrict__ ws){
    int idx = blockIdx.x;
    int t = idx % Tc; int bh = idx / Tc; int h = bh % Hc_;
    int tid = threadIdx.x;
    __shared__ float sh_h[Sc*Ec];
    __shared__ float sh_w[Sc*Sc];
    const float* hsrc = ws + WS_H1 + (size_t)idx*Sc*Ec;
    const float* al  = ws + WS_ALPHA + (size_t)idx*Sc*Sc;
    const float* adj = ws + WS_ADJ + bh*Sc*Sc;
    const float* gbd = ws + WS_BID1 + h*Sc*Sc;
    for (int i = tid; i < Sc*Ec; i += 256) sh_h[i] = hsrc[i];
    for (int i = tid; i < Sc*Sc; i += 256)
        sh_w[i] = lrelu(gbd[i]*al[i]*adj[i]);
    __syncthreads();
    for (int i = tid; i < Sc*Ec; i += 256){
        int s = i / Ec, e = i % Ec;
        float acc = 0.f;
        #pragma unroll 6
        for (int j = 0; j < Sc; j++) acc += lrelu(sh_h[j*Ec + e]*sh_w[s*Sc + j]);
        // transposed write: [bh][s][t][e]
        ws[WS_H2 + ((size_t)(bh*Sc + s)*Tc + t)*Ec + e] = lrelu(acc);
    }
}

// ------- kernel 4: per-(bh,s) temporal attention: beta + LN1 partials -------
// Q-folding: beta[t] = Hc[t]·(Wq^T·Kw) + (bq·Kw + bs) — 32 MACs/t instead of 320.
__global__ __launch_bounds__(64) void kF1(const float* __restrict__ Wq, const float* __restrict__ bq,
                   const float* __restrict__ Wk, const float* __restrict__ bk,
                   const float* __restrict__ Ws_, const float* __restrict__ bs_,
                   float* __restrict__ ws){
    int idx = blockIdx.x;                  // bh*Sc + s
    int bh = idx / Sc; int b = bh / Hc_;
    int tid = threadIdx.x;
    __shared__ float sh_Hc[Tc*33];         // row-pad 33
    __shared__ float sh_K[Tc*11];
    __shared__ float sh_Wq[TAc*32];
    __shared__ float sh_WkT[32*TAc];       // [q][d]
    __shared__ float sh_bq[TAc], sh_bk[TAc];
    __shared__ float sh_ws[Tc];
    __shared__ float sh_Kw[TAc];
    __shared__ float sh_wv[32];
    __shared__ float sh_c0;
    const float* h2c = ws + WS_H2 + (size_t)idx*Tc*Ec;   // contiguous [t][e]
    for (int i4 = tid; i4 < Tc*4; i4 += 64){
        int t = i4 >> 2, c4 = i4 & 3;
        float4 u = *(const float4*)(h2c + i4*4);
        float* d = sh_Hc + t*33 + c4*4;
        d[0] = u.x; d[1] = u.y; d[2] = u.z; d[3] = u.w;
    }
    for (int i4 = tid; i4 < Tc*4; i4 += 64){   // PE from table
        int t = i4 >> 2, c4 = i4 & 3;
        float4 u = *(const float4*)(ws + WS_PE + (size_t)(b*Tc + t)*PEc + c4*4);
        float* d = sh_Hc + t*33 + Ec + c4*4;
        d[0] = u.x; d[1] = u.y; d[2] = u.z; d[3] = u.w;
    }
    for (int i = tid; i < TAc*32; i += 64){
        sh_Wq[i] = Wq[i];
        int d = i / 32, q = i % 32;
        sh_WkT[q*TAc + d] = Wk[i];
    }
    if (tid < TAc){ sh_bq[tid] = bq[tid]; sh_bk[tid] = bk[tid]; }
    if (tid < Tc) sh_ws[tid] = Ws_[tid];
    __syncthreads();
    for (int i = tid; i < Tc*TAc; i += 64){
        int t = i / TAc, d = i % TAc;
        const float* hc = sh_Hc + t*33;
        float acc = sh_bk[d];
        #pragma unroll
        for (int q = 0; q < 32; q++) acc += hc[q]*sh_WkT[q*TAc + d];
        sh_K[t*11 + d] = acc;
    }
    __syncthreads();
    if (tid < TAc){
        float acc = 0.f;
        #pragma unroll 4
        for (int t = 0; t < Tc; t++) acc += sh_K[t*11 + tid]*sh_ws[t];
        sh_Kw[tid] = acc;
    }
    __syncthreads();
    if (tid < 32){
        float acc = 0.f;
        #pragma unroll
        for (int d = 0; d < TAc; d++) acc += sh_Wq[d*32 + tid]*sh_Kw[d];
        sh_wv[tid] = acc;
    }
    if (tid == 32){
        float acc = 0.f;
        #pragma unroll
        for (int d = 0; d < TAc; d++) acc += sh_bq[d]*sh_Kw[d];
        sh_c0 = acc;
    }
    __syncthreads();
    float bv = 0.f;
    if (tid < Tc){
        const float* hc = sh_Hc + tid*33;
        float acc = bs_[0] + sh_c0;
        #pragma unroll
        for (int q = 0; q < 32; q++) acc += hc[q]*sh_wv[q];
        bv = acc;
        ws[WS_BETA + idx*Tc + tid] = acc;
    }
    float p0 = (tid < Tc) ? bv : 0.f;
    float p1 = p0*bv;
    #pragma unroll
    for (int off = 32; off; off >>= 1){
        p0 += __shfl_down(p0, off, 64);
        p1 += __shfl_down(p1, off, 64);
    }
    if (tid == 0){
        ws[WS_PART + idx*2]     = p0;
        ws[WS_PART + idx*2 + 1] = p1;
    }
}

// ------- kernel 5: per-(bh,s) LN1-normalize + out1 + out2 + LN2 partials -------
__global__ __launch_bounds__(64) void kF2(const float* __restrict__ lnt_g, const float* __restrict__ lnt_b,
                   const float* __restrict__ Wse, const float* __restrict__ bse,
                   float* __restrict__ ws){
    int idx = blockIdx.x;
    int s = idx % Sc; int bh = idx / Sc; int b = bh / Hc_;
    int tid = threadIdx.x;
    __shared__ float sh_Hc[Tc*33];
    __shared__ float sh_beta[Tc];
    __shared__ float sh_o1[32];
    __shared__ float sh_mi[2];
    float p0 = 0.f, p1 = 0.f;
    if (tid < Sc){
        p0 = ws[WS_PART + (bh*Sc + tid)*2];
        p1 = ws[WS_PART + (bh*Sc + tid)*2 + 1];
    }
    #pragma unroll
    for (int off = 32; off; off >>= 1){
        p0 += __shfl_down(p0, off, 64);
        p1 += __shfl_down(p1, off, 64);
    }
    if (tid == 0){
        float m = p0 / (float)(Sc*Tc);
        sh_mi[0] = m;
        sh_mi[1] = rsqrtf(p1 / (float)(Sc*Tc) - m*m + EPSc);
    }
    const float* h2c = ws + WS_H2 + (size_t)idx*Tc*Ec;   // contiguous [t][e]
    for (int i4 = tid; i4 < Tc*4; i4 += 64){
        int t = i4 >> 2, c4 = i4 & 3;
        float4 u = *(const float4*)(h2c + i4*4);
        float* d = sh_Hc + t*33 + c4*4;
        d[0] = u.x; d[1] = u.y; d[2] = u.z; d[3] = u.w;
    }
    for (int i4 = tid; i4 < Tc*4; i4 += 64){   // PE from table
        int t = i4 >> 2, c4 = i4 & 3;
        float4 u = *(const float4*)(ws + WS_PE + (size_t)(b*Tc + t)*PEc + c4*4);
        float* d = sh_Hc + t*33 + Ec + c4*4;
        d[0] = u.x; d[1] = u.y; d[2] = u.z; d[3] = u.w;
    }
    __syncthreads();
    float m = sh_mi[0], inv = sh_mi[1];
    if (tid < Tc){
        float bvv = ws[WS_BETA + idx*Tc + tid];
        sh_beta[tid] = (bvv - m)*inv*lnt_g[s*Tc + tid] + lnt_b[s*Tc + tid];
    }
    __syncthreads();
    if (tid < 32){
        float acc = 0.f;
        #pragma unroll 4
        for (int t = 0; t < Tc; t++) acc += sh_beta[t]*sh_Hc[t*33 + tid];
        sh_o1[tid] = lrelu(acc);
    }
    __syncthreads();
    float v = 0.f;
    if (tid < 16){
        float acc = bse[tid];
        const float* w = Wse + tid*32;
        #pragma unroll
        for (int d = 0; d < 32; d++) acc += sh_o1[d]*w[d];
        v = lrelu(acc);
        ws[WS_OUT2 + idx*16 + tid] = v;
    }
    float q0 = v, q1 = v*v;
    #pragma unroll
    for (int off = 32; off; off >>= 1){
        q0 += __shfl_down(q0, off, 64);
        q1 += __shfl_down(q1, off, 64);
    }
    if (tid == 0){
        ws[WS_PART2 + idx*2]     = q0;
        ws[WS_PART2 + idx*2 + 1] = q1;
    }
}

// ------- kernel 6: blocks 0..31: per-(b,h) LN2 + final write; block 32: pair_sim -------
__global__ __launch_bounds__(256) void kF3s(const float* __restrict__ lns_g, const float* __restrict__ lns_b,
                    const float* __restrict__ ws, float* __restrict__ out){
    int tid = threadIdx.x;
    if (blockIdx.x == 32){
        float sq = 0.f, t2 = 0.f;
        for (int i = tid; i < Hc_*Sc*Sc; i += 256){
            float tot = 0.f;
            #pragma unroll
            for (int b = 0; b < Bc; b++){
                float v = ws[WS_ADJ + b*Hc_*Sc*Sc + i];
                sq += v*v; tot += v;
            }
            t2 += tot*tot;
        }
        __shared__ float r0[256], r1[256];
        r0[tid] = sq; r1[tid] = t2; __syncthreads();
        for (int off = 128; off; off >>= 1){
            if (tid < off){ r0[tid] += r0[tid+off]; r1[tid] += r1[tid+off]; }
            __syncthreads();
        }
        if (tid == 0)
            out[Bc*Sc*OUTc] = ((float)Bc*r0[0] - r1[0]) / 49.f / 1296.f;
        return;
    }
    int bh = blockIdx.x; int h = bh % Hc_; int b = bh / Hc_;
    __shared__ float sh_mi[2];
    if (tid < 64){
        float p0 = 0.f, p1 = 0.f;
        if (tid < Sc){
            p0 = ws[WS_PART2 + (bh*Sc + tid)*2];
            p1 = ws[WS_PART2 + (bh*Sc + tid)*2 + 1];
        }
        #pragma unroll
        for (int off = 32; off; off >>= 1){
            p0 += __shfl_down(p0, off, 64);
            p1 += __shfl_down(p1, off, 64);
        }
        if (tid == 0){
            float m = p0 / (float)(Sc*16);
            sh_mi[0] = m;
            sh_mi[1] = rsqrtf(p1 / (float)(Sc*16) - m*m + EPSc);
        }
    }
    __syncthreads();
    float m2 = sh_mi[0], inv2 = sh_mi[1];
    for (int i = tid; i < Sc*16; i += 256){
        int s = i / 16, k = i % 16;
        float v = ws[WS_OUT2 + bh*Sc*16 + i];
        out[(b*Sc + s)*OUTc + h*16 + k] = (v - m2)*inv2*lns_g[i] + lns_b[i];
    }
}

extern "C" void kernel_launch(void* const* d_in, const int* in_sizes, int n_in,
                              void* d_out, int out_size, void* d_ws, size_t ws_size,
                              hipStream_t stream){
    const float* x     = (const float*)d_in[0];
    const float* times = (const float*)d_in[1];
    const float* mask  = (const float*)d_in[2];
    const float* bn_g  = (const float*)d_in[3];
    const float* bn_b  = (const float*)d_in[4];
    const float* obs   = (const float*)d_in[5];
    const float* attn  = (const float*)d_in[6];
    const float* bidw  = (const float*)d_in[7];
    const float* projW = (const float*)d_in[8];
    const float* projb = (const float*)d_in[9];
    const float* Wq    = (const float*)d_in[10];
    const float* bq    = (const float*)d_in[11];
    const float* Wk    = (const float*)d_in[12];
    const float* bk    = (const float*)d_in[13];
    const float* Ws_   = (const float*)d_in[14];
    const float* bs_   = (const float*)d_in[15];
    const float* lnt_g = (const float*)d_in[16];
    const float* lnt_b = (const float*)d_in[17];
    const float* Wse   = (const float*)d_in[18];
    const float* bse   = (const float*)d_in[19];
    const float* lns_g = (const float*)d_in[20];
    const float* lns_b = (const float*)d_in[21];
    float* ws  = (float*)d_ws;
    float* out = (float*)d_out;

    k_layer01<<<Bc*Hc_*Tc, 256, 0, stream>>>(x, times, mask, bn_g, bn_b, obs, attn, bidw, projW, projb, ws);
    k_adjpart<<<Bc*Hc_*6, 256, 0, stream>>>(mask, bidw, ws);
    k_prune<<<Bc*Hc_*24, 256, 0, stream>>>(ws);
    k_layer1mp<<<Bc*Hc_*Tc, 256, 0, stream>>>(ws);
    kF1<<<Bc*Hc_*Sc, 64, 0, stream>>>(Wq, bq, Wk, bk, Ws_, bs_, ws);
    kF2<<<Bc*Hc_*Sc, 64, 0, stream>>>(lnt_g, lnt_b, Wse, bse, ws);
    kF3s<<<Bc*Hc_ + 1, 256, 0, stream>>>(lns_g, lns_b, ws, out);
}

// Round 6
// 190.998 us; speedup vs baseline: 1.4511x; 1.0005x over previous
//
#include <hip/hip_runtime.h>
#include <math.h>

#define Bc 8
#define Tc 60
#define Sc 36
#define Hc_ 4
#define Ec 16
#define PEc 16
#define ADc 12
#define TAc 10
#define OUTc 64
#define KEEP 648
#define EPSc 1e-5f
#define LOG1E4_8 1.15129254649702284f   // ln(10000)/8

// workspace layout (float offsets)
#define WS_H2     18176                    // B*H*S*T*E = 1105920  (layer-1 output, TRANSPOSED [bh][s][t][e])
#define WS_H1     1124096                  // 1105920              (layer-0 output, [bh][t][s][e])
#define WS_ALPHA  2230016                  // B*H*T*S*S = 2488320
#define WS_ADJ    4759808                  // B*H*S*S = 41472
#define WS_ADJP   4801280                  // B*H*6*S*S = 248832 (t-chunk partial sums)
#define WS_CNT    5050112                  // B*S = 288 (mask counts)
#define WS_PE     5050496                  // B*T*PE = 7680 (sinusoidal PE table)
#define WS_BID1   5058176                  // H*S*S = 5184 (lrelu'd layer-1 bidir Gram, per h)
// final-chain buffers overlay the (dead-by-then) ALPHA region:
#define WS_BETA   WS_ALPHA                 // B*H*S*T = 69120
#define WS_PART   (WS_ALPHA + 69120)       // B*H*S*2 = 2304
#define WS_OUT2   (WS_ALPHA + 71424)       // B*H*S*16 = 18432
#define WS_PART2  (WS_ALPHA + 89856)       // B*H*S*2 = 2304

// lrelu(v) == max(v, 0.01*v) bitwise for all finite v (2 VALU ops vs 3)
__device__ __forceinline__ float lrelu(float v){ return fmaxf(v, 0.01f*v); }

// ---- kernel 1: BN(stats+apply) + embed + layer0 (alpha0,w0,mp -> h1) + alpha1 ----
// (proven round-3 version, byte-identical)
__global__ __launch_bounds__(256) void k_layer01(const float* __restrict__ x,
                          const float* __restrict__ times,
                          const float* __restrict__ mask,
                          const float* __restrict__ bn_g,
                          const float* __restrict__ bn_b,
                          const float* __restrict__ obs_w,
                          const float* __restrict__ attn,
                          const float* __restrict__ bidw,
                          const float* __restrict__ projW,
                          const float* __restrict__ projb,
                          float* __restrict__ ws){
    int idx = blockIdx.x;                 // (b*H + h)*T + t
    int t = idx % Tc; int bh = idx / Tc; int h = bh % Hc_; int b = bh / Hc_;
    int tid = threadIdx.x;
    __shared__ float sh_h[Sc*Ec];
    __shared__ float sh_h1[Sc*Ec];
    __shared__ float sh_pe[PEc];
    __shared__ float sh_at0T[ADc*Sc];     // [d][j]
    __shared__ float sh_at1T[ADc*Sc];
    __shared__ float sh_bwT[ADc*Sc];
    __shared__ float sh_hp[Sc*28];
    __shared__ float sh_P[Sc];
    __shared__ float sh_w[Sc*Sc];
    __shared__ float sh_xn[Sc];
    __shared__ float sh_m[Sc];
    __shared__ float sred[8];
    float s0 = 0.f, s1 = 0.f;
    for (int i = tid; i < Bc*Sc; i += 256){
        float v = x[((i/Sc)*Tc + t)*Sc + (i%Sc)];
        s0 += v; s1 += v*v;
    }
    #pragma unroll
    for (int off = 32; off; off >>= 1){
        s0 += __shfl_down(s0, off, 64);
        s1 += __shfl_down(s1, off, 64);
    }
    if ((tid & 63) == 0){ sred[(tid>>6)*2] = s0; sred[(tid>>6)*2 + 1] = s1; }
    if (tid >= 64 && tid < 80){
        int q = tid - 64; int j = q >> 1;
        float ang = times[b*Tc + t] * expf(-(float)j * LOG1E4_8);
        float pv = (q & 1) ? cosf(ang) : sinf(ang);
        sh_pe[q] = pv;
        if (h == 0) ws[WS_PE + (b*Tc + t)*PEc + q] = pv;   // persist PE table
    }
    for (int i = tid; i < ADc*Sc; i += 256){
        int d = i / Sc, j = i % Sc;
        sh_at0T[i] = attn[h*Sc*ADc + j*ADc + d];
        sh_at1T[i] = attn[(Hc_ + h)*Sc*ADc + j*ADc + d];
        sh_bwT[i]  = bidw[h*Sc*ADc + j*ADc + d];
    }
    __syncthreads();
    float mu  = (sred[0]+sred[2]+sred[4]+sred[6]) / (float)(Bc*Sc);
    float var = (sred[1]+sred[3]+sred[5]+sred[7]) / (float)(Bc*Sc) - mu*mu;
    if (tid < Sc){
        float xv = x[(b*Tc + t)*Sc + tid];
        sh_xn[tid] = (xv - mu) * rsqrtf(var + EPSc) * bn_g[t] + bn_b[t];
        sh_m[tid]  = mask[(b*Tc + t)*Sc + tid];
    }
    __syncthreads();
    for (int i = tid; i < Sc*Ec; i += 256){
        int s = i / Ec, e = i % Ec;
        sh_h[i] = lrelu(sh_xn[s]*obs_w[s*64 + h*Ec + e]) * sh_m[s];
    }
    __syncthreads();
    for (int i = tid; i < Sc*28; i += 256){
        int s = i / 28, d = i % 28;
        float acc = projb[d];
        const float* w = projW + d*Ec;
        const float* hh = sh_h + s*Ec;
        #pragma unroll
        for (int e = 0; e < Ec; e++) acc += hh[e]*w[e];
        sh_hp[i] = acc;
    }
    __syncthreads();
    if (tid < Sc){
        const float* hp = sh_hp + tid*28 + ADc;
        float p = 0.f;
        #pragma unroll
        for (int d = 0; d < PEc; d++) p += hp[d]*sh_pe[d];
        sh_P[tid] = p;
    }
    __syncthreads();
    for (int i = tid; i < Sc*Sc; i += 256){
        int s = i / Sc, j = i % Sc;
        const float* hp = sh_hp + s*28;
        float acc = sh_P[s];
        float bd = 0.f;
        #pragma unroll
        for (int d = 0; d < ADc; d++){
            acc += hp[d]*sh_at0T[d*Sc + j];
            bd  += sh_bwT[d*Sc + s]*sh_bwT[d*Sc + j];
        }
        sh_w[i] = lrelu(lrelu(bd)*lrelu(acc));
    }
    __syncthreads();
    float* h1g = ws + WS_H1 + (size_t)idx*Sc*Ec;
    for (int i = tid; i < Sc*Ec; i += 256){
        int s = i / Ec, e = i % Ec;
        float acc = 0.f;
        #pragma unroll 6
        for (int j = 0; j < Sc; j++) acc += lrelu(sh_h[j*Ec + e]*sh_w[s*Sc + j]);
        float v = lrelu(acc);
        sh_h1[i] = v;
        h1g[i] = v;
    }
    __syncthreads();
    for (int i = tid; i < Sc*28; i += 256){
        int s = i / 28, d = i % 28;
        float acc = projb[d];
        const float* w = projW + d*Ec;
        const float* hh = sh_h1 + s*Ec;
        #pragma unroll
        for (int e = 0; e < Ec; e++) acc += hh[e]*w[e];
        sh_hp[i] = acc;
    }
    __syncthreads();
    if (tid < Sc){
        const float* hp = sh_hp + tid*28 + ADc;
        float p = 0.f;
        #pragma unroll
        for (int d = 0; d < PEc; d++) p += hp[d]*sh_pe[d];
        sh_P[tid] = p;
    }
    __syncthreads();
    float* adst = ws + WS_ALPHA + (size_t)idx*Sc*Sc;
    for (int i = tid; i < Sc*Sc; i += 256){
        int s = i / Sc, j = i % Sc;
        const float* hp = sh_hp + s*28;
        float acc = sh_P[s];
        #pragma unroll
        for (int d = 0; d < ADc; d++) acc += hp[d]*sh_at1T[d*Sc + j];
        adst[i] = lrelu(acc);
    }
}

// ---- kernel 2a: per-(bh, t-chunk, column-quarter) partial t-sum of alpha (768 blocks);
//      designated blocks: mask counts + layer-1 bidir Gram hoist ----
__global__ __launch_bounds__(256) void k_adjpart(const float* __restrict__ mask,
                                                 const float* __restrict__ bidw,
                                                 float* __restrict__ ws){
    int blk = blockIdx.x;                 // bh*24 + chunk*4 + quarter
    int quar = blk & 3; int chunk = (blk >> 2) % 6; int bh = blk / 24;
    int tid = threadIdx.x;
    const float4* a = (const float4*)(ws + WS_ALPHA + (size_t)bh*Tc*Sc*Sc) + (size_t)chunk*10*324;
    float4* p = (float4*)(ws + WS_ADJP + (size_t)(bh*6 + chunk)*Sc*Sc);
    for (int c = quar*81 + tid; c < quar*81 + 81; c += 256){
        float4 acc = make_float4(0.f, 0.f, 0.f, 0.f);
        #pragma unroll
        for (int tt = 0; tt < 10; tt++){
            float4 u = a[(size_t)tt*324 + c];
            acc.x += u.x; acc.y += u.y; acc.z += u.z; acc.w += u.w;
        }
        p[c] = acc;
    }
    if (chunk == 0 && quar == 0 && (bh & 3) == 0 && tid < Sc){
        int b = bh >> 2;
        float c = 0.f;
        #pragma unroll 4
        for (int t = 0; t < Tc; t++) c += mask[(b*Tc + t)*Sc + tid];
        ws[WS_CNT + b*Sc + tid] = c;
    }
    // layer-1 bidir Gram: 4 distinct matrices (per h); d-ascending sum == old
    // k_layer1mp order -> bit-identical.
    if (chunk == 5 && quar == 1 && bh < Hc_){
        int h = bh;
        const float* bw = bidw + (Hc_ + h)*Sc*ADc;
        for (int i = tid; i < Sc*Sc; i += 256){
            int s = i / Sc, j = i % Sc;
            float bd = 0.f;
            #pragma unroll
            for (int d = 0; d < ADc; d++) bd += bw[s*ADc + d]*bw[j*ADc + d];
            ws[WS_BID1 + h*Sc*Sc + i] = lrelu(bd);
        }
    }
}

// ---- kernel 2b: stable-rank prune, 4-way split scan (768 blocks) ----
__global__ __launch_bounds__(256) void k_prune(float* __restrict__ ws){
    int bh = blockIdx.x / 24; int chunk = blockIdx.x % 24;
    int b = bh >> 2;
    int tid = threadIdx.x;
    __shared__ __align__(16) float sh_v[Sc*Sc];
    __shared__ float sh_cnt[Sc];
    const float4* p = (const float4*)(ws + WS_ADJP + (size_t)bh*6*Sc*Sc);
    for (int c = tid; c < 324; c += 256){
        float4 acc = make_float4(0.f, 0.f, 0.f, 0.f);
        #pragma unroll
        for (int q = 0; q < 6; q++){
            float4 u = p[(size_t)q*324 + c];
            acc.x += u.x; acc.y += u.y; acc.z += u.z; acc.w += u.w;
        }
        ((float4*)sh_v)[c] = acc;
    }
    if (tid < Sc) sh_cnt[tid] = ws[WS_CNT + b*Sc + tid];
    __syncthreads();
    for (int i = tid; i < Sc*Sc; i += 256){
        int s = i / Sc;
        sh_v[i] = lrelu(sh_v[i] / sh_cnt[s]);
    }
    __syncthreads();
    int r = tid >> 2; if (r > 53) r = 53;
    int part = tid & 3;
    int i = chunk*54 + r;
    float v = sh_v[i];
    const float4* v4 = (const float4*)sh_v + part*81;
    int a0 = part*324;
    int cnt = 0;
    #pragma unroll 9
    for (int j = 0; j < 81; j++){
        float4 u = v4[j];
        int k = a0 + j*4;
        cnt += (int)(u.x < v) + ((int)(u.x == v) & (int)(k   < i));
        cnt += (int)(u.y < v) + ((int)(u.y == v) & (int)(k+1 < i));
        cnt += (int)(u.z < v) + ((int)(u.z == v) & (int)(k+2 < i));
        cnt += (int)(u.w < v) + ((int)(u.w == v) & (int)(k+3 < i));
    }
    cnt += __shfl_down(cnt, 2, 4);
    cnt += __shfl_down(cnt, 1, 4);
    if (part == 0 && tid < 216)
        ws[WS_ADJ + bh*Sc*Sc + i] = (cnt >= KEEP) ? v : 0.f;
}

// ---------------- kernel 3: layer 1 message passing (h2 written TRANSPOSED) ----------------
__global__ __launch_bounds__(256) void k_layer1mp(float* __restrict__ ws){
    int idx = blockIdx.x;
    int t = idx % Tc; int bh = idx / Tc; int h = bh % Hc_;
    int tid = threadIdx.x;
    __shared__ float sh_h[Sc*Ec];
    __shared__ float sh_w[Sc*Sc];
    const float* hsrc = ws + WS_H1 + (size_t)idx*Sc*Ec;
    const float* al  = ws + WS_ALPHA + (size_t)idx*Sc*Sc;
    const float* adj = ws + WS_ADJ + bh*Sc*Sc;
    const float* gbd = ws + WS_BID1 + h*Sc*Sc;
    for (int i = tid; i < Sc*Ec; i += 256) sh_h[i] = hsrc[i];
    for (int i = tid; i < Sc*Sc; i += 256)
        sh_w[i] = lrelu(gbd[i]*al[i]*adj[i]);
    __syncthreads();
    for (int i = tid; i < Sc*Ec; i += 256){
        int s = i / Ec, e = i % Ec;
        float acc = 0.f;
        #pragma unroll 6
        for (int j = 0; j < Sc; j++) acc += lrelu(sh_h[j*Ec + e]*sh_w[s*Sc + j]);
        // transposed write: [bh][s][t][e]
        ws[WS_H2 + ((size_t)(bh*Sc + s)*Tc + t)*Ec + e] = lrelu(acc);
    }
}

// ------- kernel 4: per-(bh,s) temporal attention: beta + LN1 partials -------
// Now 256 threads (4 waves) per block for latency hiding; per-element math and
// wave-0 reductions identical to the proven 64-thread version -> bit-identical.
__global__ __launch_bounds__(256) void kF1(const float* __restrict__ Wq, const float* __restrict__ bq,
                   const float* __restrict__ Wk, const float* __restrict__ bk,
                   const float* __restrict__ Ws_, const float* __restrict__ bs_,
                   float* __restrict__ ws){
    int idx = blockIdx.x;                  // bh*Sc + s
    int bh = idx / Sc; int b = bh / Hc_;
    int tid = threadIdx.x;
    __shared__ float sh_Hc[Tc*33];         // row-pad 33
    __shared__ float sh_K[Tc*11];
    __shared__ float sh_Wq[TAc*32];
    __shared__ float sh_WkT[32*TAc];       // [q][d]
    __shared__ float sh_bq[TAc], sh_bk[TAc];
    __shared__ float sh_ws[Tc];
    __shared__ float sh_Kw[TAc];
    __shared__ float sh_wv[32];
    __shared__ float sh_c0;
    const float* h2c = ws + WS_H2 + (size_t)idx*Tc*Ec;   // contiguous [t][e]
    for (int i4 = tid; i4 < Tc*4; i4 += 256){
        int t = i4 >> 2, c4 = i4 & 3;
        float4 u = *(const float4*)(h2c + i4*4);
        float* d = sh_Hc + t*33 + c4*4;
        d[0] = u.x; d[1] = u.y; d[2] = u.z; d[3] = u.w;
    }
    for (int i4 = tid; i4 < Tc*4; i4 += 256){   // PE from table
        int t = i4 >> 2, c4 = i4 & 3;
        float4 u = *(const float4*)(ws + WS_PE + (size_t)(b*Tc + t)*PEc + c4*4);
        float* d = sh_Hc + t*33 + Ec + c4*4;
        d[0] = u.x; d[1] = u.y; d[2] = u.z; d[3] = u.w;
    }
    for (int i = tid; i < TAc*32; i += 256){
        sh_Wq[i] = Wq[i];
        int d = i / 32, q = i % 32;
        sh_WkT[q*TAc + d] = Wk[i];
    }
    if (tid < TAc){ sh_bq[tid] = bq[tid]; sh_bk[tid] = bk[tid]; }
    if (tid < Tc) sh_ws[tid] = Ws_[tid];
    __syncthreads();
    for (int i = tid; i < Tc*TAc; i += 256){
        int t = i / TAc, d = i % TAc;
        const float* hc = sh_Hc + t*33;
        float acc = sh_bk[d];
        #pragma unroll
        for (int q = 0; q < 32; q++) acc += hc[q]*sh_WkT[q*TAc + d];
        sh_K[t*11 + d] = acc;
    }
    __syncthreads();
    if (tid < TAc){
        float acc = 0.f;
        #pragma unroll 4
        for (int t = 0; t < Tc; t++) acc += sh_K[t*11 + tid]*sh_ws[t];
        sh_Kw[tid] = acc;
    }
    __syncthreads();
    if (tid < 32){
        float acc = 0.f;
        #pragma unroll
        for (int d = 0; d < TAc; d++) acc += sh_Wq[d*32 + tid]*sh_Kw[d];
        sh_wv[tid] = acc;
    }
    if (tid == 32){
        float acc = 0.f;
        #pragma unroll
        for (int d = 0; d < TAc; d++) acc += sh_bq[d]*sh_Kw[d];
        sh_c0 = acc;
    }
    __syncthreads();
    if (tid < 64){
        float bv = 0.f;
        if (tid < Tc){
            const float* hc = sh_Hc + tid*33;
            float acc = bs_[0] + sh_c0;
            #pragma unroll
            for (int q = 0; q < 32; q++) acc += hc[q]*sh_wv[q];
            bv = acc;
            ws[WS_BETA + idx*Tc + tid] = acc;
        }
        float p0 = (tid < Tc) ? bv : 0.f;
        float p1 = p0*bv;
        #pragma unroll
        for (int off = 32; off; off >>= 1){
            p0 += __shfl_down(p0, off, 64);
            p1 += __shfl_down(p1, off, 64);
        }
        if (tid == 0){
            ws[WS_PART + idx*2]     = p0;
            ws[WS_PART + idx*2 + 1] = p1;
        }
    }
}

// ------- kernel 5: per-(bh,s) LN1-normalize + out1 + out2 + LN2 partials -------
// 256 threads (4 waves); wave-0 reductions identical to the 64-thread version.
__global__ __launch_bounds__(256) void kF2(const float* __restrict__ lnt_g, const float* __restrict__ lnt_b,
                   const float* __restrict__ Wse, const float* __restrict__ bse,
                   float* __restrict__ ws){
    int idx = blockIdx.x;
    int s = idx % Sc; int bh = idx / Sc; int b = bh / Hc_;
    int tid = threadIdx.x;
    __shared__ float sh_Hc[Tc*33];
    __shared__ float sh_beta[Tc];
    __shared__ float sh_o1[32];
    __shared__ float sh_mi[2];
    if (tid < 64){
        float p0 = 0.f, p1 = 0.f;
        if (tid < Sc){
            p0 = ws[WS_PART + (bh*Sc + tid)*2];
            p1 = ws[WS_PART + (bh*Sc + tid)*2 + 1];
        }
        #pragma unroll
        for (int off = 32; off; off >>= 1){
            p0 += __shfl_down(p0, off, 64);
            p1 += __shfl_down(p1, off, 64);
        }
        if (tid == 0){
            float m = p0 / (float)(Sc*Tc);
            sh_mi[0] = m;
            sh_mi[1] = rsqrtf(p1 / (float)(Sc*Tc) - m*m + EPSc);
        }
    }
    const float* h2c = ws + WS_H2 + (size_t)idx*Tc*Ec;   // contiguous [t][e]
    for (int i4 = tid; i4 < Tc*4; i4 += 256){
        int t = i4 >> 2, c4 = i4 & 3;
        float4 u = *(const float4*)(h2c + i4*4);
        float* d = sh_Hc + t*33 + c4*4;
        d[0] = u.x; d[1] = u.y; d[2] = u.z; d[3] = u.w;
    }
    for (int i4 = tid; i4 < Tc*4; i4 += 256){   // PE from table
        int t = i4 >> 2, c4 = i4 & 3;
        float4 u = *(const float4*)(ws + WS_PE + (size_t)(b*Tc + t)*PEc + c4*4);
        float* d = sh_Hc + t*33 + Ec + c4*4;
        d[0] = u.x; d[1] = u.y; d[2] = u.z; d[3] = u.w;
    }
    __syncthreads();
    float m = sh_mi[0], inv = sh_mi[1];
    if (tid < Tc){
        float bvv = ws[WS_BETA + idx*Tc + tid];
        sh_beta[tid] = (bvv - m)*inv*lnt_g[s*Tc + tid] + lnt_b[s*Tc + tid];
    }
    __syncthreads();
    if (tid < 32){
        float acc = 0.f;
        #pragma unroll 4
        for (int t = 0; t < Tc; t++) acc += sh_beta[t]*sh_Hc[t*33 + tid];
        sh_o1[tid] = lrelu(acc);
    }
    __syncthreads();
    if (tid < 64){
        float v = 0.f;
        if (tid < 16){
            float acc = bse[tid];
            const float* w = Wse + tid*32;
            #pragma unroll
            for (int d = 0; d < 32; d++) acc += sh_o1[d]*w[d];
            v = lrelu(acc);
            ws[WS_OUT2 + idx*16 + tid] = v;
        }
        float q0 = v, q1 = v*v;
        #pragma unroll
        for (int off = 32; off; off >>= 1){
            q0 += __shfl_down(q0, off, 64);
            q1 += __shfl_down(q1, off, 64);
        }
        if (tid == 0){
            ws[WS_PART2 + idx*2]     = q0;
            ws[WS_PART2 + idx*2 + 1] = q1;
        }
    }
}

// ------- kernel 6: blocks 0..31: per-(b,h) LN2 + final write; block 32: pair_sim -------
__global__ __launch_bounds__(256) void kF3s(const float* __restrict__ lns_g, const float* __restrict__ lns_b,
                    const float* __restrict__ ws, float* __restrict__ out){
    int tid = threadIdx.x;
    if (blockIdx.x == 32){
        float sq = 0.f, t2 = 0.f;
        for (int i = tid; i < Hc_*Sc*Sc; i += 256){
            float tot = 0.f;
            #pragma unroll
            for (int b = 0; b < Bc; b++){
                float v = ws[WS_ADJ + b*Hc_*Sc*Sc + i];
                sq += v*v; tot += v;
            }
            t2 += tot*tot;
        }
        __shared__ float r0[256], r1[256];
        r0[tid] = sq; r1[tid] = t2; __syncthreads();
        for (int off = 128; off; off >>= 1){
            if (tid < off){ r0[tid] += r0[tid+off]; r1[tid] += r1[tid+off]; }
            __syncthreads();
        }
        if (tid == 0)
            out[Bc*Sc*OUTc] = ((float)Bc*r0[0] - r1[0]) / 49.f / 1296.f;
        return;
    }
    int bh = blockIdx.x; int h = bh % Hc_; int b = bh / Hc_;
    __shared__ float sh_mi[2];
    if (tid < 64){
        float p0 = 0.f, p1 = 0.f;
        if (tid < Sc){
            p0 = ws[WS_PART2 + (bh*Sc + tid)*2];
            p1 = ws[WS_PART2 + (bh*Sc + tid)*2 + 1];
        }
        #pragma unroll
        for (int off = 32; off; off >>= 1){
            p0 += __shfl_down(p0, off, 64);
            p1 += __shfl_down(p1, off, 64);
        }
        if (tid == 0){
            float m = p0 / (float)(Sc*16);
            sh_mi[0] = m;
            sh_mi[1] = rsqrtf(p1 / (float)(Sc*16) - m*m + EPSc);
        }
    }
    __syncthreads();
    float m2 = sh_mi[0], inv2 = sh_mi[1];
    for (int i = tid; i < Sc*16; i += 256){
        int s = i / 16, k = i % 16;
        float v = ws[WS_OUT2 + bh*Sc*16 + i];
        out[(b*Sc + s)*OUTc + h*16 + k] = (v - m2)*inv2*lns_g[i] + lns_b[i];
    }
}

extern "C" void kernel_launch(void* const* d_in, const int* in_sizes, int n_in,
                              void* d_out, int out_size, void* d_ws, size_t ws_size,
                              hipStream_t stream){
    const float* x     = (const float*)d_in[0];
    const float* times = (const float*)d_in[1];
    const float* mask  = (const float*)d_in[2];
    const float* bn_g  = (const float*)d_in[3];
    const float* bn_b  = (const float*)d_in[4];
    const float* obs   = (const float*)d_in[5];
    const float* attn  = (const float*)d_in[6];
    const float* bidw  = (const float*)d_in[7];
    const float* projW = (const float*)d_in[8];
    const float* projb = (const float*)d_in[9];
    const float* Wq    = (const float*)d_in[10];
    const float* bq    = (const float*)d_in[11];
    const float* Wk    = (const float*)d_in[12];
    const float* bk    = (const float*)d_in[13];
    const float* Ws_   = (const float*)d_in[14];
    const float* bs_   = (const float*)d_in[15];
    const float* lnt_g = (const float*)d_in[16];
    const float* lnt_b = (const float*)d_in[17];
    const float* Wse   = (const float*)d_in[18];
    const float* bse   = (const float*)d_in[19];
    const float* lns_g = (const float*)d_in[20];
    const float* lns_b = (const float*)d_in[21];
    float* ws  = (float*)d_ws;
    float* out = (float*)d_out;

    k_layer01<<<Bc*Hc_*Tc, 256, 0, stream>>>(x, times, mask, bn_g, bn_b, obs, attn, bidw, projW, projb, ws);
    k_adjpart<<<Bc*Hc_*24, 256, 0, stream>>>(mask, bidw, ws);
    k_prune<<<Bc*Hc_*24, 256, 0, stream>>>(ws);
    k_layer1mp<<<Bc*Hc_*Tc, 256, 0, stream>>>(ws);
    kF1<<<Bc*Hc_*Sc, 256, 0, stream>>>(Wq, bq, Wk, bk, Ws_, bs_, ws);
    kF2<<<Bc*Hc_*Sc, 256, 0, stream>>>(lnt_g, lnt_b, Wse, bse, ws);
    kF3s<<<Bc*Hc_ + 1, 256, 0, stream>>>(lns_g, lns_b, ws, out);
}

// Round 7
// 186.316 us; speedup vs baseline: 1.4875x; 1.0251x over previous
//
#include <hip/hip_runtime.h>
#include <math.h>

#define Bc 8
#define Tc 60
#define Sc 36
#define Hc_ 4
#define Ec 16
#define PEc 16
#define ADc 12
#define TAc 10
#define OUTc 64
#define KEEP 648
#define EPSc 1e-5f
#define LOG1E4_8 1.15129254649702284f   // ln(10000)/8

// workspace layout (float offsets)
#define WS_H2     18176                    // B*H*S*T*E = 1105920  (layer-1 output, TRANSPOSED [bh][s][t][e])
#define WS_H1     1124096                  // 1105920              (layer-0 output, [bh][t][s][e])
#define WS_ALPHA  2230016                  // B*H*T*S*S = 2488320
#define WS_ADJ    4759808                  // B*H*S*S = 41472
#define WS_ADJP   4801280                  // B*H*6*S*S = 248832 (t-chunk partial sums)
#define WS_CNT    5050112                  // B*S = 288 (mask counts)
#define WS_PE     5050496                  // B*T*PE = 7680 (sinusoidal PE table)
#define WS_BID1   5058176                  // H*S*S = 5184 (lrelu'd layer-1 bidir Gram, per h)
// final-chain buffers overlay the (dead-by-then) ALPHA region:
#define WS_BETA   WS_ALPHA                 // B*H*S*T = 69120
#define WS_PART   (WS_ALPHA + 69120)       // B*H*S*2 = 2304
#define WS_OUT2   (WS_ALPHA + 71424)       // B*H*S*16 = 18432
#define WS_PART2  (WS_ALPHA + 89856)       // B*H*S*2 = 2304

// lrelu(v) == max(v, 0.01*v) bitwise for all finite v (2 VALU ops vs 3)
__device__ __forceinline__ float lrelu(float v){ return fmaxf(v, 0.01f*v); }
__device__ __forceinline__ float4 lrelu4(float4 v){
    return make_float4(lrelu(v.x), lrelu(v.y), lrelu(v.z), lrelu(v.w));
}

// ---- kernel 1: BN(stats+apply) + embed + layer0 (alpha0,w0,mp -> h1) + alpha1 ----
// float4-vectorized LDS access in all hot loops; per-output FP order identical
// to the proven scalar version (j/d/e ascending) -> bit-identical outputs.
__global__ __launch_bounds__(256) void k_layer01(const float* __restrict__ x,
                          const float* __restrict__ times,
                          const float* __restrict__ mask,
                          const float* __restrict__ bn_g,
                          const float* __restrict__ bn_b,
                          const float* __restrict__ obs_w,
                          const float* __restrict__ attn,
                          const float* __restrict__ bidw,
                          const float* __restrict__ projW,
                          const float* __restrict__ projb,
                          float* __restrict__ ws){
    int idx = blockIdx.x;                 // (b*H + h)*T + t
    int t = idx % Tc; int bh = idx / Tc; int h = bh % Hc_; int b = bh / Hc_;
    int tid = threadIdx.x;
    __shared__ __align__(16) float sh_h[Sc*Ec];
    __shared__ __align__(16) float sh_h1[Sc*Ec];
    __shared__ float sh_pe[PEc];
    __shared__ __align__(16) float sh_at0T[ADc*Sc];   // [d][j]
    __shared__ __align__(16) float sh_at1T[ADc*Sc];
    __shared__ __align__(16) float sh_bwT[ADc*Sc];
    __shared__ float sh_hp[Sc*28];
    __shared__ float sh_P[Sc];
    __shared__ __align__(16) float sh_w[Sc*Sc];
    __shared__ float sh_xn[Sc];
    __shared__ float sh_m[Sc];
    __shared__ float sred[8];
    float s0 = 0.f, s1 = 0.f;
    for (int i = tid; i < Bc*Sc; i += 256){
        float v = x[((i/Sc)*Tc + t)*Sc + (i%Sc)];
        s0 += v; s1 += v*v;
    }
    #pragma unroll
    for (int off = 32; off; off >>= 1){
        s0 += __shfl_down(s0, off, 64);
        s1 += __shfl_down(s1, off, 64);
    }
    if ((tid & 63) == 0){ sred[(tid>>6)*2] = s0; sred[(tid>>6)*2 + 1] = s1; }
    if (tid >= 64 && tid < 80){
        int q = tid - 64; int j = q >> 1;
        float ang = times[b*Tc + t] * expf(-(float)j * LOG1E4_8);
        float pv = (q & 1) ? cosf(ang) : sinf(ang);
        sh_pe[q] = pv;
        if (h == 0) ws[WS_PE + (b*Tc + t)*PEc + q] = pv;   // persist PE table
    }
    for (int i = tid; i < ADc*Sc; i += 256){
        int d = i / Sc, j = i % Sc;
        sh_at0T[i] = attn[h*Sc*ADc + j*ADc + d];
        sh_at1T[i] = attn[(Hc_ + h)*Sc*ADc + j*ADc + d];
        sh_bwT[i]  = bidw[h*Sc*ADc + j*ADc + d];
    }
    __syncthreads();
    float mu  = (sred[0]+sred[2]+sred[4]+sred[6]) / (float)(Bc*Sc);
    float var = (sred[1]+sred[3]+sred[5]+sred[7]) / (float)(Bc*Sc) - mu*mu;
    if (tid < Sc){
        float xv = x[(b*Tc + t)*Sc + tid];
        sh_xn[tid] = (xv - mu) * rsqrtf(var + EPSc) * bn_g[t] + bn_b[t];
        sh_m[tid]  = mask[(b*Tc + t)*Sc + tid];
    }
    __syncthreads();
    // embed: 144 float4 outputs
    for (int i4 = tid; i4 < 144; i4 += 256){
        int s = i4 >> 2, e0 = (i4 & 3) << 2;
        float4 ow = *(const float4*)(obs_w + s*64 + h*Ec + e0);
        float xn = sh_xn[s], mm = sh_m[s];
        float4 r;
        r.x = lrelu(xn*ow.x)*mm; r.y = lrelu(xn*ow.y)*mm;
        r.z = lrelu(xn*ow.z)*mm; r.w = lrelu(xn*ow.w)*mm;
        *(float4*)(sh_h + s*Ec + e0) = r;
    }
    __syncthreads();
    // proj(h): float4 reads of hh and projW rows, sequential e order preserved
    for (int i = tid; i < Sc*28; i += 256){
        int s = i / 28, d = i % 28;
        const float4* hh4 = (const float4*)(sh_h + s*Ec);
        const float4* w4  = (const float4*)(projW + d*Ec);
        float acc = projb[d];
        #pragma unroll
        for (int q = 0; q < 4; q++){
            float4 hv = hh4[q], wv = w4[q];
            acc += hv.x*wv.x; acc += hv.y*wv.y; acc += hv.z*wv.z; acc += hv.w*wv.w;
        }
        sh_hp[i] = acc;
    }
    __syncthreads();
    if (tid < Sc){
        const float* hp = sh_hp + tid*28 + ADc;
        float p = 0.f;
        #pragma unroll
        for (int d = 0; d < PEc; d++) p += hp[d]*sh_pe[d];
        sh_P[tid] = p;
    }
    __syncthreads();
    // alpha0 + bidir Gram + w0: 324 float4 outputs
    for (int i4 = tid; i4 < 324; i4 += 256){
        int s = i4 / 9, j0 = (i4 % 9) << 2;
        const float* hp = sh_hp + s*28;
        float ps = sh_P[s];
        float4 acc = make_float4(ps, ps, ps, ps);
        float4 bd = make_float4(0.f, 0.f, 0.f, 0.f);
        #pragma unroll
        for (int d = 0; d < ADc; d++){
            float hpd = hp[d];
            float4 a = *(const float4*)(sh_at0T + d*Sc + j0);
            acc.x += hpd*a.x; acc.y += hpd*a.y; acc.z += hpd*a.z; acc.w += hpd*a.w;
            float bws = sh_bwT[d*Sc + s];
            float4 bj = *(const float4*)(sh_bwT + d*Sc + j0);
            bd.x += bws*bj.x; bd.y += bws*bj.y; bd.z += bws*bj.z; bd.w += bws*bj.w;
        }
        float4 r;
        r.x = lrelu(lrelu(bd.x)*lrelu(acc.x));
        r.y = lrelu(lrelu(bd.y)*lrelu(acc.y));
        r.z = lrelu(lrelu(bd.z)*lrelu(acc.z));
        r.w = lrelu(lrelu(bd.w)*lrelu(acc.w));
        *(float4*)(sh_w + s*Sc + j0) = r;
    }
    __syncthreads();
    // message passing -> h1: 144 float4 outputs
    float* h1g = ws + WS_H1 + (size_t)idx*Sc*Ec;
    for (int i4 = tid; i4 < 144; i4 += 256){
        int s = i4 >> 2, e0 = (i4 & 3) << 2;
        float4 acc = make_float4(0.f, 0.f, 0.f, 0.f);
        const float* wr = sh_w + s*Sc;
        #pragma unroll 6
        for (int j = 0; j < Sc; j++){
            float4 hv = *(const float4*)(sh_h + j*Ec + e0);
            float w = wr[j];
            acc.x += lrelu(hv.x*w); acc.y += lrelu(hv.y*w);
            acc.z += lrelu(hv.z*w); acc.w += lrelu(hv.w*w);
        }
        float4 v = lrelu4(acc);
        *(float4*)(sh_h1 + s*Ec + e0) = v;
        *(float4*)(h1g + s*Ec + e0) = v;
    }
    __syncthreads();
    // proj(h1)
    for (int i = tid; i < Sc*28; i += 256){
        int s = i / 28, d = i % 28;
        const float4* hh4 = (const float4*)(sh_h1 + s*Ec);
        const float4* w4  = (const float4*)(projW + d*Ec);
        float acc = projb[d];
        #pragma unroll
        for (int q = 0; q < 4; q++){
            float4 hv = hh4[q], wv = w4[q];
            acc += hv.x*wv.x; acc += hv.y*wv.y; acc += hv.z*wv.z; acc += hv.w*wv.w;
        }
        sh_hp[i] = acc;
    }
    __syncthreads();
    if (tid < Sc){
        const float* hp = sh_hp + tid*28 + ADc;
        float p = 0.f;
        #pragma unroll
        for (int d = 0; d < PEc; d++) p += hp[d]*sh_pe[d];
        sh_P[tid] = p;
    }
    __syncthreads();
    // alpha1: 324 float4 outputs, written straight to global
    float* adst = ws + WS_ALPHA + (size_t)idx*Sc*Sc;
    for (int i4 = tid; i4 < 324; i4 += 256){
        int s = i4 / 9, j0 = (i4 % 9) << 2;
        const float* hp = sh_hp + s*28;
        float ps = sh_P[s];
        float4 acc = make_float4(ps, ps, ps, ps);
        #pragma unroll
        for (int d = 0; d < ADc; d++){
            float hpd = hp[d];
            float4 a = *(const float4*)(sh_at1T + d*Sc + j0);
            acc.x += hpd*a.x; acc.y += hpd*a.y; acc.z += hpd*a.z; acc.w += hpd*a.w;
        }
        *(float4*)(adst + s*Sc + j0) = lrelu4(acc);
    }
}

// ---- kernel 2a: per-(bh, t-chunk, column-quarter) partial t-sum of alpha (768 blocks);
//      designated blocks: mask counts + layer-1 bidir Gram hoist ----
__global__ __launch_bounds__(256) void k_adjpart(const float* __restrict__ mask,
                                                 const float* __restrict__ bidw,
                                                 float* __restrict__ ws){
    int blk = blockIdx.x;                 // bh*24 + chunk*4 + quarter
    int quar = blk & 3; int chunk = (blk >> 2) % 6; int bh = blk / 24;
    int tid = threadIdx.x;
    const float4* a = (const float4*)(ws + WS_ALPHA + (size_t)bh*Tc*Sc*Sc) + (size_t)chunk*10*324;
    float4* p = (float4*)(ws + WS_ADJP + (size_t)(bh*6 + chunk)*Sc*Sc);
    for (int c = quar*81 + tid; c < quar*81 + 81; c += 256){
        float4 acc = make_float4(0.f, 0.f, 0.f, 0.f);
        #pragma unroll
        for (int tt = 0; tt < 10; tt++){
            float4 u = a[(size_t)tt*324 + c];
            acc.x += u.x; acc.y += u.y; acc.z += u.z; acc.w += u.w;
        }
        p[c] = acc;
    }
    if (chunk == 0 && quar == 0 && (bh & 3) == 0 && tid < Sc){
        int b = bh >> 2;
        float c = 0.f;
        #pragma unroll 4
        for (int t = 0; t < Tc; t++) c += mask[(b*Tc + t)*Sc + tid];
        ws[WS_CNT + b*Sc + tid] = c;
    }
    // layer-1 bidir Gram: 4 distinct matrices (per h); d-ascending sum == old
    // k_layer1mp order -> bit-identical.
    if (chunk == 5 && quar == 1 && bh < Hc_){
        int h = bh;
        const float* bw = bidw + (Hc_ + h)*Sc*ADc;
        for (int i = tid; i < Sc*Sc; i += 256){
            int s = i / Sc, j = i % Sc;
            float bd = 0.f;
            #pragma unroll
            for (int d = 0; d < ADc; d++) bd += bw[s*ADc + d]*bw[j*ADc + d];
            ws[WS_BID1 + h*Sc*Sc + i] = lrelu(bd);
        }
    }
}

// ---- kernel 2b: stable-rank prune, 4-way split scan (768 blocks) ----
__global__ __launch_bounds__(256) void k_prune(float* __restrict__ ws){
    int bh = blockIdx.x / 24; int chunk = blockIdx.x % 24;
    int b = bh >> 2;
    int tid = threadIdx.x;
    __shared__ __align__(16) float sh_v[Sc*Sc];
    __shared__ float sh_cnt[Sc];
    const float4* p = (const float4*)(ws + WS_ADJP + (size_t)bh*6*Sc*Sc);
    for (int c = tid; c < 324; c += 256){
        float4 acc = make_float4(0.f, 0.f, 0.f, 0.f);
        #pragma unroll
        for (int q = 0; q < 6; q++){
            float4 u = p[(size_t)q*324 + c];
            acc.x += u.x; acc.y += u.y; acc.z += u.z; acc.w += u.w;
        }
        ((float4*)sh_v)[c] = acc;
    }
    if (tid < Sc) sh_cnt[tid] = ws[WS_CNT + b*Sc + tid];
    __syncthreads();
    for (int i = tid; i < Sc*Sc; i += 256){
        int s = i / Sc;
        sh_v[i] = lrelu(sh_v[i] / sh_cnt[s]);
    }
    __syncthreads();
    int r = tid >> 2; if (r > 53) r = 53;
    int part = tid & 3;
    int i = chunk*54 + r;
    float v = sh_v[i];
    const float4* v4 = (const float4*)sh_v + part*81;
    int a0 = part*324;
    int cnt = 0;
    #pragma unroll 9
    for (int j = 0; j < 81; j++){
        float4 u = v4[j];
        int k = a0 + j*4;
        cnt += (int)(u.x < v) + ((int)(u.x == v) & (int)(k   < i));
        cnt += (int)(u.y < v) + ((int)(u.y == v) & (int)(k+1 < i));
        cnt += (int)(u.z < v) + ((int)(u.z == v) & (int)(k+2 < i));
        cnt += (int)(u.w < v) + ((int)(u.w == v) & (int)(k+3 < i));
    }
    cnt += __shfl_down(cnt, 2, 4);
    cnt += __shfl_down(cnt, 1, 4);
    if (part == 0 && tid < 216)
        ws[WS_ADJ + bh*Sc*Sc + i] = (cnt >= KEEP) ? v : 0.f;
}

// ---------------- kernel 3: layer 1 message passing (h2 written TRANSPOSED) ----------------
// float4-vectorized staging, w-combine, and mp loops; FP order identical.
__global__ __launch_bounds__(256) void k_layer1mp(float* __restrict__ ws){
    int idx = blockIdx.x;
    int t = idx % Tc; int bh = idx / Tc; int h = bh % Hc_;
    int tid = threadIdx.x;
    __shared__ __align__(16) float sh_h[Sc*Ec];
    __shared__ __align__(16) float sh_w[Sc*Sc];
    const float4* hsrc4 = (const float4*)(ws + WS_H1 + (size_t)idx*Sc*Ec);
    const float4* al4  = (const float4*)(ws + WS_ALPHA + (size_t)idx*Sc*Sc);
    const float4* adj4 = (const float4*)(ws + WS_ADJ + bh*Sc*Sc);
    const float4* gbd4 = (const float4*)(ws + WS_BID1 + h*Sc*Sc);
    for (int i4 = tid; i4 < 144; i4 += 256) ((float4*)sh_h)[i4] = hsrc4[i4];
    for (int i4 = tid; i4 < 324; i4 += 256){
        float4 g = gbd4[i4], a = al4[i4], ad = adj4[i4];
        float4 r;
        r.x = lrelu(g.x*a.x*ad.x); r.y = lrelu(g.y*a.y*ad.y);
        r.z = lrelu(g.z*a.z*ad.z); r.w = lrelu(g.w*a.w*ad.w);
        ((float4*)sh_w)[i4] = r;
    }
    __syncthreads();
    for (int i4 = tid; i4 < 144; i4 += 256){
        int s = i4 >> 2, e0 = (i4 & 3) << 2;
        float4 acc = make_float4(0.f, 0.f, 0.f, 0.f);
        const float* wr = sh_w + s*Sc;
        #pragma unroll 6
        for (int j = 0; j < Sc; j++){
            float4 hv = *(const float4*)(sh_h + j*Ec + e0);
            float w = wr[j];
            acc.x += lrelu(hv.x*w); acc.y += lrelu(hv.y*w);
            acc.z += lrelu(hv.z*w); acc.w += lrelu(hv.w*w);
        }
        // transposed write: [bh][s][t][e]
        *(float4*)(ws + WS_H2 + ((size_t)(bh*Sc + s)*Tc + t)*Ec + e0) = lrelu4(acc);
    }
}

// ------- kernel 4: per-(bh,s) temporal attention: beta + LN1 partials -------
__global__ __launch_bounds__(256) void kF1(const float* __restrict__ Wq, const float* __restrict__ bq,
                   const float* __restrict__ Wk, const float* __restrict__ bk,
                   const float* __restrict__ Ws_, const float* __restrict__ bs_,
                   float* __restrict__ ws){
    int idx = blockIdx.x;                  // bh*Sc + s
    int bh = idx / Sc; int b = bh / Hc_;
    int tid = threadIdx.x;
    __shared__ float sh_Hc[Tc*33];         // row-pad 33
    __shared__ float sh_K[Tc*11];
    __shared__ float sh_Wq[TAc*32];
    __shared__ float sh_WkT[32*TAc];       // [q][d]
    __shared__ float sh_bq[TAc], sh_bk[TAc];
    __shared__ float sh_ws[Tc];
    __shared__ float sh_Kw[TAc];
    __shared__ float sh_wv[32];
    __shared__ float sh_c0;
    const float* h2c = ws + WS_H2 + (size_t)idx*Tc*Ec;   // contiguous [t][e]
    for (int i4 = tid; i4 < Tc*4; i4 += 256){
        int t = i4 >> 2, c4 = i4 & 3;
        float4 u = *(const float4*)(h2c + i4*4);
        float* d = sh_Hc + t*33 + c4*4;
        d[0] = u.x; d[1] = u.y; d[2] = u.z; d[3] = u.w;
    }
    for (int i4 = tid; i4 < Tc*4; i4 += 256){   // PE from table
        int t = i4 >> 2, c4 = i4 & 3;
        float4 u = *(const float4*)(ws + WS_PE + (size_t)(b*Tc + t)*PEc + c4*4);
        float* d = sh_Hc + t*33 + Ec + c4*4;
        d[0] = u.x; d[1] = u.y; d[2] = u.z; d[3] = u.w;
    }
    for (int i = tid; i < TAc*32; i += 256){
        sh_Wq[i] = Wq[i];
        int d = i / 32, q = i % 32;
        sh_WkT[q*TAc + d] = Wk[i];
    }
    if (tid < TAc){ sh_bq[tid] = bq[tid]; sh_bk[tid] = bk[tid]; }
    if (tid < Tc) sh_ws[tid] = Ws_[tid];
    __syncthreads();
    for (int i = tid; i < Tc*TAc; i += 256){
        int t = i / TAc, d = i % TAc;
        const float* hc = sh_Hc + t*33;
        float acc = sh_bk[d];
        #pragma unroll
        for (int q = 0; q < 32; q++) acc += hc[q]*sh_WkT[q*TAc + d];
        sh_K[t*11 + d] = acc;
    }
    __syncthreads();
    if (tid < TAc){
        float acc = 0.f;
        #pragma unroll 4
        for (int t = 0; t < Tc; t++) acc += sh_K[t*11 + tid]*sh_ws[t];
        sh_Kw[tid] = acc;
    }
    __syncthreads();
    if (tid < 32){
        float acc = 0.f;
        #pragma unroll
        for (int d = 0; d < TAc; d++) acc += sh_Wq[d*32 + tid]*sh_Kw[d];
        sh_wv[tid] = acc;
    }
    if (tid == 32){
        float acc = 0.f;
        #pragma unroll
        for (int d = 0; d < TAc; d++) acc += sh_bq[d]*sh_Kw[d];
        sh_c0 = acc;
    }
    __syncthreads();
    if (tid < 64){
        float bv = 0.f;
        if (tid < Tc){
            const float* hc = sh_Hc + tid*33;
            float acc = bs_[0] + sh_c0;
            #pragma unroll
            for (int q = 0; q < 32; q++) acc += hc[q]*sh_wv[q];
            bv = acc;
            ws[WS_BETA + idx*Tc + tid] = acc;
        }
        float p0 = (tid < Tc) ? bv : 0.f;
        float p1 = p0*bv;
        #pragma unroll
        for (int off = 32; off; off >>= 1){
            p0 += __shfl_down(p0, off, 64);
            p1 += __shfl_down(p1, off, 64);
        }
        if (tid == 0){
            ws[WS_PART + idx*2]     = p0;
            ws[WS_PART + idx*2 + 1] = p1;
        }
    }
}

// ------- kernel 5: per-(bh,s) LN1-normalize + out1 + out2 + LN2 partials -------
__global__ __launch_bounds__(256) void kF2(const float* __restrict__ lnt_g, const float* __restrict__ lnt_b,
                   const float* __restrict__ Wse, const float* __restrict__ bse,
                   float* __restrict__ ws){
    int idx = blockIdx.x;
    int s = idx % Sc; int bh = idx / Sc; int b = bh / Hc_;
    int tid = threadIdx.x;
    __shared__ float sh_Hc[Tc*33];
    __shared__ float sh_beta[Tc];
    __shared__ float sh_o1[32];
    __shared__ float sh_mi[2];
    if (tid < 64){
        float p0 = 0.f, p1 = 0.f;
        if (tid < Sc){
            p0 = ws[WS_PART + (bh*Sc + tid)*2];
            p1 = ws[WS_PART + (bh*Sc + tid)*2 + 1];
        }
        #pragma unroll
        for (int off = 32; off; off >>= 1){
            p0 += __shfl_down(p0, off, 64);
            p1 += __shfl_down(p1, off, 64);
        }
        if (tid == 0){
            float m = p0 / (float)(Sc*Tc);
            sh_mi[0] = m;
            sh_mi[1] = rsqrtf(p1 / (float)(Sc*Tc) - m*m + EPSc);
        }
    }
    const float* h2c = ws + WS_H2 + (size_t)idx*Tc*Ec;   // contiguous [t][e]
    for (int i4 = tid; i4 < Tc*4; i4 += 256){
        int t = i4 >> 2, c4 = i4 & 3;
        float4 u = *(const float4*)(h2c + i4*4);
        float* d = sh_Hc + t*33 + c4*4;
        d[0] = u.x; d[1] = u.y; d[2] = u.z; d[3] = u.w;
    }
    for (int i4 = tid; i4 < Tc*4; i4 += 256){   // PE from table
        int t = i4 >> 2, c4 = i4 & 3;
        float4 u = *(const float4*)(ws + WS_PE + (size_t)(b*Tc + t)*PEc + c4*4);
        float* d = sh_Hc + t*33 + Ec + c4*4;
        d[0] = u.x; d[1] = u.y; d[2] = u.z; d[3] = u.w;
    }
    __syncthreads();
    float m = sh_mi[0], inv = sh_mi[1];
    if (tid < Tc){
        float bvv = ws[WS_BETA + idx*Tc + tid];
        sh_beta[tid] = (bvv - m)*inv*lnt_g[s*Tc + tid] + lnt_b[s*Tc + tid];
    }
    __syncthreads();
    if (tid < 32){
        float acc = 0.f;
        #pragma unroll 4
        for (int t = 0; t < Tc; t++) acc += sh_beta[t]*sh_Hc[t*33 + tid];
        sh_o1[tid] = lrelu(acc);
    }
    __syncthreads();
    if (tid < 64){
        float v = 0.f;
        if (tid < 16){
            float acc = bse[tid];
            const float* w = Wse + tid*32;
            #pragma unroll
            for (int d = 0; d < 32; d++) acc += sh_o1[d]*w[d];
            v = lrelu(acc);
            ws[WS_OUT2 + idx*16 + tid] = v;
        }
        float q0 = v, q1 = v*v;
        #pragma unroll
        for (int off = 32; off; off >>= 1){
            q0 += __shfl_down(q0, off, 64);
            q1 += __shfl_down(q1, off, 64);
        }
        if (tid == 0){
            ws[WS_PART2 + idx*2]     = q0;
            ws[WS_PART2 + idx*2 + 1] = q1;
        }
    }
}

// ------- kernel 6: blocks 0..31: per-(b,h) LN2 + final write; block 32: pair_sim -------
__global__ __launch_bounds__(256) void kF3s(const float* __restrict__ lns_g, const float* __restrict__ lns_b,
                    const float* __restrict__ ws, float* __restrict__ out){
    int tid = threadIdx.x;
    if (blockIdx.x == 32){
        float sq = 0.f, t2 = 0.f;
        for (int i = tid; i < Hc_*Sc*Sc; i += 256){
            float tot = 0.f;
            #pragma unroll
            for (int b = 0; b < Bc; b++){
                float v = ws[WS_ADJ + b*Hc_*Sc*Sc + i];
                sq += v*v; tot += v;
            }
            t2 += tot*tot;
        }
        __shared__ float r0[256], r1[256];
        r0[tid] = sq; r1[tid] = t2; __syncthreads();
        for (int off = 128; off; off >>= 1){
            if (tid < off){ r0[tid] += r0[tid+off]; r1[tid] += r1[tid+off]; }
            __syncthreads();
        }
        if (tid == 0)
            out[Bc*Sc*OUTc] = ((float)Bc*r0[0] - r1[0]) / 49.f / 1296.f;
        return;
    }
    int bh = blockIdx.x; int h = bh % Hc_; int b = bh / Hc_;
    __shared__ float sh_mi[2];
    if (tid < 64){
        float p0 = 0.f, p1 = 0.f;
        if (tid < Sc){
            p0 = ws[WS_PART2 + (bh*Sc + tid)*2];
            p1 = ws[WS_PART2 + (bh*Sc + tid)*2 + 1];
        }
        #pragma unroll
        for (int off = 32; off; off >>= 1){
            p0 += __shfl_down(p0, off, 64);
            p1 += __shfl_down(p1, off, 64);
        }
        if (tid == 0){
            float m = p0 / (float)(Sc*16);
            sh_mi[0] = m;
            sh_mi[1] = rsqrtf(p1 / (float)(Sc*16) - m*m + EPSc);
        }
    }
    __syncthreads();
    float m2 = sh_mi[0], inv2 = sh_mi[1];
    for (int i = tid; i < Sc*16; i += 256){
        int s = i / 16, k = i % 16;
        float v = ws[WS_OUT2 + bh*Sc*16 + i];
        out[(b*Sc + s)*OUTc + h*16 + k] = (v - m2)*inv2*lns_g[i] + lns_b[i];
    }
}

extern "C" void kernel_launch(void* const* d_in, const int* in_sizes, int n_in,
                              void* d_out, int out_size, void* d_ws, size_t ws_size,
                              hipStream_t stream){
    const float* x     = (const float*)d_in[0];
    const float* times = (const float*)d_in[1];
    const float* mask  = (const float*)d_in[2];
    const float* bn_g  = (const float*)d_in[3];
    const float* bn_b  = (const float*)d_in[4];
    const float* obs   = (const float*)d_in[5];
    const float* attn  = (const float*)d_in[6];
    const float* bidw  = (const float*)d_in[7];
    const float* projW = (const float*)d_in[8];
    const float* projb = (const float*)d_in[9];
    const float* Wq    = (const float*)d_in[10];
    const float* bq    = (const float*)d_in[11];
    const float* Wk    = (const float*)d_in[12];
    const float* bk    = (const float*)d_in[13];
    const float* Ws_   = (const float*)d_in[14];
    const float* bs_   = (const float*)d_in[15];
    const float* lnt_g = (const float*)d_in[16];
    const float* lnt_b = (const float*)d_in[17];
    const float* Wse   = (const float*)d_in[18];
    const float* bse   = (const float*)d_in[19];
    const float* lns_g = (const float*)d_in[20];
    const float* lns_b = (const float*)d_in[21];
    float* ws  = (float*)d_ws;
    float* out = (float*)d_out;

    k_layer01<<<Bc*Hc_*Tc, 256, 0, stream>>>(x, times, mask, bn_g, bn_b, obs, attn, bidw, projW, projb, ws);
    k_adjpart<<<Bc*Hc_*24, 256, 0, stream>>>(mask, bidw, ws);
    k_prune<<<Bc*Hc_*24, 256, 0, stream>>>(ws);
    k_layer1mp<<<Bc*Hc_*Tc, 256, 0, stream>>>(ws);
    kF1<<<Bc*Hc_*Sc, 256, 0, stream>>>(Wq, bq, Wk, bk, Ws_, bs_, ws);
    kF2<<<Bc*Hc_*Sc, 256, 0, stream>>>(lnt_g, lnt_b, Wse, bse, ws);
    kF3s<<<Bc*Hc_ + 1, 256, 0, stream>>>(lns_g, lns_b, ws, out);
}

// Round 8
// 182.552 us; speedup vs baseline: 1.5182x; 1.0206x over previous
//
#include <hip/hip_runtime.h>
#include <math.h>

#define Bc 8
#define Tc 60
#define Sc 36
#define Hc_ 4
#define Ec 16
#define PEc 16
#define ADc 12
#define TAc 10
#define OUTc 64
#define KEEP 648
#define EPSc 1e-5f
#define LOG1E4_8 1.15129254649702284f   // ln(10000)/8

// workspace layout (float offsets)
#define WS_H2     18176                    // B*H*S*T*E = 1105920  (layer-1 output, TRANSPOSED [bh][s][t][e])
#define WS_H1     1124096                  // 1105920              (layer-0 output, [bh][t][s][e])
#define WS_ALPHA  2230016                  // B*H*T*S*S = 2488320
#define WS_ADJ    4759808                  // B*H*S*S = 41472
#define WS_ADJP   4801280                  // B*H*6*S*S = 248832 (t-chunk partial sums)
#define WS_CNT    5050112                  // B*S = 288 (mask counts)
#define WS_PE     5050496                  // B*T*PE = 7680 (sinusoidal PE table)
#define WS_BID1   5058176                  // H*S*S = 5184 (lrelu'd layer-1 bidir Gram, per h)
// final-chain buffers overlay the (dead-by-then) ALPHA region:
#define WS_BETA   WS_ALPHA                 // B*H*S*T = 69120
#define WS_PART   (WS_ALPHA + 69120)       // B*H*S*2 = 2304
#define WS_OUT2   (WS_ALPHA + 71424)       // B*H*S*16 = 18432
#define WS_PART2  (WS_ALPHA + 89856)       // B*H*S*2 = 2304

// lrelu(v) == max(v, 0.01*v) bitwise for all finite v (2 VALU ops vs 3)
__device__ __forceinline__ float lrelu(float v){ return fmaxf(v, 0.01f*v); }
__device__ __forceinline__ float4 lrelu4(float4 v){
    return make_float4(lrelu(v.x), lrelu(v.y), lrelu(v.z), lrelu(v.w));
}

// ---- kernel 1: BN(stats+apply) + embed + layer0 (alpha0,w0,mp -> h1) + alpha1 ----
// float2 mp/embed loops (288 units -> all 256 threads active); P inlined into
// alpha loops (2 barriers removed). Per-output FP order identical -> bit-identical.
__global__ __launch_bounds__(256) void k_layer01(const float* __restrict__ x,
                          const float* __restrict__ times,
                          const float* __restrict__ mask,
                          const float* __restrict__ bn_g,
                          const float* __restrict__ bn_b,
                          const float* __restrict__ obs_w,
                          const float* __restrict__ attn,
                          const float* __restrict__ bidw,
                          const float* __restrict__ projW,
                          const float* __restrict__ projb,
                          float* __restrict__ ws){
    int idx = blockIdx.x;                 // (b*H + h)*T + t
    int t = idx % Tc; int bh = idx / Tc; int h = bh % Hc_; int b = bh / Hc_;
    int tid = threadIdx.x;
    __shared__ __align__(16) float sh_h[Sc*Ec];
    __shared__ __align__(16) float sh_h1[Sc*Ec];
    __shared__ float sh_pe[PEc];
    __shared__ __align__(16) float sh_at0T[ADc*Sc];   // [d][j]
    __shared__ __align__(16) float sh_at1T[ADc*Sc];
    __shared__ __align__(16) float sh_bwT[ADc*Sc];
    __shared__ float sh_hp[Sc*28];
    __shared__ __align__(16) float sh_w[Sc*Sc];
    __shared__ float sh_xn[Sc];
    __shared__ float sh_m[Sc];
    __shared__ float sred[8];
    float s0 = 0.f, s1 = 0.f;
    for (int i = tid; i < Bc*Sc; i += 256){
        float v = x[((i/Sc)*Tc + t)*Sc + (i%Sc)];
        s0 += v; s1 += v*v;
    }
    #pragma unroll
    for (int off = 32; off; off >>= 1){
        s0 += __shfl_down(s0, off, 64);
        s1 += __shfl_down(s1, off, 64);
    }
    if ((tid & 63) == 0){ sred[(tid>>6)*2] = s0; sred[(tid>>6)*2 + 1] = s1; }
    if (tid >= 64 && tid < 80){
        int q = tid - 64; int j = q >> 1;
        float ang = times[b*Tc + t] * expf(-(float)j * LOG1E4_8);
        float pv = (q & 1) ? cosf(ang) : sinf(ang);
        sh_pe[q] = pv;
        if (h == 0) ws[WS_PE + (b*Tc + t)*PEc + q] = pv;   // persist PE table
    }
    for (int i = tid; i < ADc*Sc; i += 256){
        int d = i / Sc, j = i % Sc;
        sh_at0T[i] = attn[h*Sc*ADc + j*ADc + d];
        sh_at1T[i] = attn[(Hc_ + h)*Sc*ADc + j*ADc + d];
        sh_bwT[i]  = bidw[h*Sc*ADc + j*ADc + d];
    }
    __syncthreads();
    float mu  = (sred[0]+sred[2]+sred[4]+sred[6]) / (float)(Bc*Sc);
    float var = (sred[1]+sred[3]+sred[5]+sred[7]) / (float)(Bc*Sc) - mu*mu;
    if (tid < Sc){
        float xv = x[(b*Tc + t)*Sc + tid];
        sh_xn[tid] = (xv - mu) * rsqrtf(var + EPSc) * bn_g[t] + bn_b[t];
        sh_m[tid]  = mask[(b*Tc + t)*Sc + tid];
    }
    __syncthreads();
    // embed: 288 float2 outputs (all threads active)
    for (int i2 = tid; i2 < 288; i2 += 256){
        int s = i2 >> 3, e0 = (i2 & 7) << 1;
        float2 ow = *(const float2*)(obs_w + s*64 + h*Ec + e0);
        float xn = sh_xn[s], mm = sh_m[s];
        float2 r;
        r.x = lrelu(xn*ow.x)*mm; r.y = lrelu(xn*ow.y)*mm;
        *(float2*)(sh_h + s*Ec + e0) = r;
    }
    __syncthreads();
    // proj(h): float4 reads, sequential e order preserved
    for (int i = tid; i < Sc*28; i += 256){
        int s = i / 28, d = i % 28;
        const float4* hh4 = (const float4*)(sh_h + s*Ec);
        const float4* w4  = (const float4*)(projW + d*Ec);
        float acc = projb[d];
        #pragma unroll
        for (int q = 0; q < 4; q++){
            float4 hv = hh4[q], wv = w4[q];
            acc += hv.x*wv.x; acc += hv.y*wv.y; acc += hv.z*wv.z; acc += hv.w*wv.w;
        }
        sh_hp[i] = acc;
    }
    __syncthreads();
    // alpha0 + bidir Gram + w0: 324 float4 outputs; P inlined (same d-order)
    for (int i4 = tid; i4 < 324; i4 += 256){
        int s = i4 / 9, j0 = (i4 % 9) << 2;
        const float* hp = sh_hp + s*28;
        float ps = 0.f;
        #pragma unroll
        for (int d = 0; d < PEc; d++) ps += hp[ADc + d]*sh_pe[d];
        float4 acc = make_float4(ps, ps, ps, ps);
        float4 bd = make_float4(0.f, 0.f, 0.f, 0.f);
        #pragma unroll
        for (int d = 0; d < ADc; d++){
            float hpd = hp[d];
            float4 a = *(const float4*)(sh_at0T + d*Sc + j0);
            acc.x += hpd*a.x; acc.y += hpd*a.y; acc.z += hpd*a.z; acc.w += hpd*a.w;
            float bws = sh_bwT[d*Sc + s];
            float4 bj = *(const float4*)(sh_bwT + d*Sc + j0);
            bd.x += bws*bj.x; bd.y += bws*bj.y; bd.z += bws*bj.z; bd.w += bws*bj.w;
        }
        float4 r;
        r.x = lrelu(lrelu(bd.x)*lrelu(acc.x));
        r.y = lrelu(lrelu(bd.y)*lrelu(acc.y));
        r.z = lrelu(lrelu(bd.z)*lrelu(acc.z));
        r.w = lrelu(lrelu(bd.w)*lrelu(acc.w));
        *(float4*)(sh_w + s*Sc + j0) = r;
    }
    __syncthreads();
    // message passing -> h1: 288 float2 outputs (all threads active)
    float* h1g = ws + WS_H1 + (size_t)idx*Sc*Ec;
    for (int i2 = tid; i2 < 288; i2 += 256){
        int s = i2 >> 3, e0 = (i2 & 7) << 1;
        float2 acc = make_float2(0.f, 0.f);
        const float* wr = sh_w + s*Sc;
        #pragma unroll 6
        for (int j = 0; j < Sc; j++){
            float2 hv = *(const float2*)(sh_h + j*Ec + e0);
            float w = wr[j];
            acc.x += lrelu(hv.x*w); acc.y += lrelu(hv.y*w);
        }
        float2 v; v.x = lrelu(acc.x); v.y = lrelu(acc.y);
        *(float2*)(sh_h1 + s*Ec + e0) = v;
        *(float2*)(h1g + s*Ec + e0) = v;
    }
    __syncthreads();
    // proj(h1)
    for (int i = tid; i < Sc*28; i += 256){
        int s = i / 28, d = i % 28;
        const float4* hh4 = (const float4*)(sh_h1 + s*Ec);
        const float4* w4  = (const float4*)(projW + d*Ec);
        float acc = projb[d];
        #pragma unroll
        for (int q = 0; q < 4; q++){
            float4 hv = hh4[q], wv = w4[q];
            acc += hv.x*wv.x; acc += hv.y*wv.y; acc += hv.z*wv.z; acc += hv.w*wv.w;
        }
        sh_hp[i] = acc;
    }
    __syncthreads();
    // alpha1: 324 float4 outputs, P inlined, written straight to global
    float* adst = ws + WS_ALPHA + (size_t)idx*Sc*Sc;
    for (int i4 = tid; i4 < 324; i4 += 256){
        int s = i4 / 9, j0 = (i4 % 9) << 2;
        const float* hp = sh_hp + s*28;
        float ps = 0.f;
        #pragma unroll
        for (int d = 0; d < PEc; d++) ps += hp[ADc + d]*sh_pe[d];
        float4 acc = make_float4(ps, ps, ps, ps);
        #pragma unroll
        for (int d = 0; d < ADc; d++){
            float hpd = hp[d];
            float4 a = *(const float4*)(sh_at1T + d*Sc + j0);
            acc.x += hpd*a.x; acc.y += hpd*a.y; acc.z += hpd*a.z; acc.w += hpd*a.w;
        }
        *(float4*)(adst + s*Sc + j0) = lrelu4(acc);
    }
}

// ---- kernel 2a: per-(bh, t-chunk, column-quarter) partial t-sum of alpha (768 blocks);
//      designated blocks: mask counts + layer-1 bidir Gram hoist ----
__global__ __launch_bounds__(256) void k_adjpart(const float* __restrict__ mask,
                                                 const float* __restrict__ bidw,
                                                 float* __restrict__ ws){
    int blk = blockIdx.x;                 // bh*24 + chunk*4 + quarter
    int quar = blk & 3; int chunk = (blk >> 2) % 6; int bh = blk / 24;
    int tid = threadIdx.x;
    const float4* a = (const float4*)(ws + WS_ALPHA + (size_t)bh*Tc*Sc*Sc) + (size_t)chunk*10*324;
    float4* p = (float4*)(ws + WS_ADJP + (size_t)(bh*6 + chunk)*Sc*Sc);
    for (int c = quar*81 + tid; c < quar*81 + 81; c += 256){
        float4 acc = make_float4(0.f, 0.f, 0.f, 0.f);
        #pragma unroll
        for (int tt = 0; tt < 10; tt++){
            float4 u = a[(size_t)tt*324 + c];
            acc.x += u.x; acc.y += u.y; acc.z += u.z; acc.w += u.w;
        }
        p[c] = acc;
    }
    if (chunk == 0 && quar == 0 && (bh & 3) == 0 && tid < Sc){
        int b = bh >> 2;
        float c = 0.f;
        #pragma unroll 4
        for (int t = 0; t < Tc; t++) c += mask[(b*Tc + t)*Sc + tid];
        ws[WS_CNT + b*Sc + tid] = c;
    }
    // layer-1 bidir Gram: 4 distinct matrices (per h); d-ascending sum == old
    // k_layer1mp order -> bit-identical.
    if (chunk == 5 && quar == 1 && bh < Hc_){
        int h = bh;
        const float* bw = bidw + (Hc_ + h)*Sc*ADc;
        for (int i = tid; i < Sc*Sc; i += 256){
            int s = i / Sc, j = i % Sc;
            float bd = 0.f;
            #pragma unroll
            for (int d = 0; d < ADc; d++) bd += bw[s*ADc + d]*bw[j*ADc + d];
            ws[WS_BID1 + h*Sc*Sc + i] = lrelu(bd);
        }
    }
}

// ---- kernel 2b: stable-rank prune, 4-way split scan (768 blocks) ----
__global__ __launch_bounds__(256) void k_prune(float* __restrict__ ws){
    int bh = blockIdx.x / 24; int chunk = blockIdx.x % 24;
    int b = bh >> 2;
    int tid = threadIdx.x;
    __shared__ __align__(16) float sh_v[Sc*Sc];
    __shared__ float sh_cnt[Sc];
    const float4* p = (const float4*)(ws + WS_ADJP + (size_t)bh*6*Sc*Sc);
    for (int c = tid; c < 324; c += 256){
        float4 acc = make_float4(0.f, 0.f, 0.f, 0.f);
        #pragma unroll
        for (int q = 0; q < 6; q++){
            float4 u = p[(size_t)q*324 + c];
            acc.x += u.x; acc.y += u.y; acc.z += u.z; acc.w += u.w;
        }
        ((float4*)sh_v)[c] = acc;
    }
    if (tid < Sc) sh_cnt[tid] = ws[WS_CNT + b*Sc + tid];
    __syncthreads();
    for (int i = tid; i < Sc*Sc; i += 256){
        int s = i / Sc;
        sh_v[i] = lrelu(sh_v[i] / sh_cnt[s]);
    }
    __syncthreads();
    int r = tid >> 2; if (r > 53) r = 53;
    int part = tid & 3;
    int i = chunk*54 + r;
    float v = sh_v[i];
    const float4* v4 = (const float4*)sh_v + part*81;
    int a0 = part*324;
    int cnt = 0;
    #pragma unroll 9
    for (int j = 0; j < 81; j++){
        float4 u = v4[j];
        int k = a0 + j*4;
        cnt += (int)(u.x < v) + ((int)(u.x == v) & (int)(k   < i));
        cnt += (int)(u.y < v) + ((int)(u.y == v) & (int)(k+1 < i));
        cnt += (int)(u.z < v) + ((int)(u.z == v) & (int)(k+2 < i));
        cnt += (int)(u.w < v) + ((int)(u.w == v) & (int)(k+3 < i));
    }
    cnt += __shfl_down(cnt, 2, 4);
    cnt += __shfl_down(cnt, 1, 4);
    if (part == 0 && tid < 216)
        ws[WS_ADJ + bh*Sc*Sc + i] = (cnt >= KEEP) ? v : 0.f;
}

// ---------------- kernel 3: layer 1 message passing (h2 written TRANSPOSED) ----------------
// float2 mp loop (288 units -> all 256 threads active); FP order identical.
__global__ __launch_bounds__(256) void k_layer1mp(float* __restrict__ ws){
    int idx = blockIdx.x;
    int t = idx % Tc; int bh = idx / Tc; int h = bh % Hc_;
    int tid = threadIdx.x;
    __shared__ __align__(16) float sh_h[Sc*Ec];
    __shared__ __align__(16) float sh_w[Sc*Sc];
    const float4* hsrc4 = (const float4*)(ws + WS_H1 + (size_t)idx*Sc*Ec);
    const float4* al4  = (const float4*)(ws + WS_ALPHA + (size_t)idx*Sc*Sc);
    const float4* adj4 = (const float4*)(ws + WS_ADJ + bh*Sc*Sc);
    const float4* gbd4 = (const float4*)(ws + WS_BID1 + h*Sc*Sc);
    for (int i4 = tid; i4 < 144; i4 += 256) ((float4*)sh_h)[i4] = hsrc4[i4];
    for (int i4 = tid; i4 < 324; i4 += 256){
        float4 g = gbd4[i4], a = al4[i4], ad = adj4[i4];
        float4 r;
        r.x = lrelu(g.x*a.x*ad.x); r.y = lrelu(g.y*a.y*ad.y);
        r.z = lrelu(g.z*a.z*ad.z); r.w = lrelu(g.w*a.w*ad.w);
        ((float4*)sh_w)[i4] = r;
    }
    __syncthreads();
    for (int i2 = tid; i2 < 288; i2 += 256){
        int s = i2 >> 3, e0 = (i2 & 7) << 1;
        float2 acc = make_float2(0.f, 0.f);
        const float* wr = sh_w + s*Sc;
        #pragma unroll 6
        for (int j = 0; j < Sc; j++){
            float2 hv = *(const float2*)(sh_h + j*Ec + e0);
            float w = wr[j];
            acc.x += lrelu(hv.x*w); acc.y += lrelu(hv.y*w);
        }
        float2 v; v.x = lrelu(acc.x); v.y = lrelu(acc.y);
        // transposed write: [bh][s][t][e]
        *(float2*)(ws + WS_H2 + ((size_t)(bh*Sc + s)*Tc + t)*Ec + e0) = v;
    }
}

// ------- kernel 4: per-(bh,s) temporal attention: beta + LN1 partials -------
__global__ __launch_bounds__(256) void kF1(const float* __restrict__ Wq, const float* __restrict__ bq,
                   const float* __restrict__ Wk, const float* __restrict__ bk,
                   const float* __restrict__ Ws_, const float* __restrict__ bs_,
                   float* __restrict__ ws){
    int idx = blockIdx.x;                  // bh*Sc + s
    int bh = idx / Sc; int b = bh / Hc_;
    int tid = threadIdx.x;
    __shared__ float sh_Hc[Tc*33];         // row-pad 33
    __shared__ float sh_K[Tc*11];
    __shared__ float sh_Wq[TAc*32];
    __shared__ float sh_WkT[32*TAc];       // [q][d]
    __shared__ float sh_bq[TAc], sh_bk[TAc];
    __shared__ float sh_ws[Tc];
    __shared__ float sh_Kw[TAc];
    __shared__ float sh_wv[32];
    __shared__ float sh_c0;
    const float* h2c = ws + WS_H2 + (size_t)idx*Tc*Ec;   // contiguous [t][e]
    for (int i4 = tid; i4 < Tc*4; i4 += 256){
        int t = i4 >> 2, c4 = i4 & 3;
        float4 u = *(const float4*)(h2c + i4*4);
        float* d = sh_Hc + t*33 + c4*4;
        d[0] = u.x; d[1] = u.y; d[2] = u.z; d[3] = u.w;
    }
    for (int i4 = tid; i4 < Tc*4; i4 += 256){   // PE from table
        int t = i4 >> 2, c4 = i4 & 3;
        float4 u = *(const float4*)(ws + WS_PE + (size_t)(b*Tc + t)*PEc + c4*4);
        float* d = sh_Hc + t*33 + Ec + c4*4;
        d[0] = u.x; d[1] = u.y; d[2] = u.z; d[3] = u.w;
    }
    for (int i = tid; i < TAc*32; i += 256){
        sh_Wq[i] = Wq[i];
        int d = i / 32, q = i % 32;
        sh_WkT[q*TAc + d] = Wk[i];
    }
    if (tid < TAc){ sh_bq[tid] = bq[tid]; sh_bk[tid] = bk[tid]; }
    if (tid < Tc) sh_ws[tid] = Ws_[tid];
    __syncthreads();
    for (int i = tid; i < Tc*TAc; i += 256){
        int t = i / TAc, d = i % TAc;
        const float* hc = sh_Hc + t*33;
        float acc = sh_bk[d];
        #pragma unroll
        for (int q = 0; q < 32; q++) acc += hc[q]*sh_WkT[q*TAc + d];
        sh_K[t*11 + d] = acc;
    }
    __syncthreads();
    if (tid < TAc){
        float acc = 0.f;
        #pragma unroll 4
        for (int t = 0; t < Tc; t++) acc += sh_K[t*11 + tid]*sh_ws[t];
        sh_Kw[tid] = acc;
    }
    __syncthreads();
    if (tid < 32){
        float acc = 0.f;
        #pragma unroll
        for (int d = 0; d < TAc; d++) acc += sh_Wq[d*32 + tid]*sh_Kw[d];
        sh_wv[tid] = acc;
    }
    if (tid == 32){
        float acc = 0.f;
        #pragma unroll
        for (int d = 0; d < TAc; d++) acc += sh_bq[d]*sh_Kw[d];
        sh_c0 = acc;
    }
    __syncthreads();
    if (tid < 64){
        float bv = 0.f;
        if (tid < Tc){
            const float* hc = sh_Hc + tid*33;
            float acc = bs_[0] + sh_c0;
            #pragma unroll
            for (int q = 0; q < 32; q++) acc += hc[q]*sh_wv[q];
            bv = acc;
            ws[WS_BETA + idx*Tc + tid] = acc;
        }
        float p0 = (tid < Tc) ? bv : 0.f;
        float p1 = p0*bv;
        #pragma unroll
        for (int off = 32; off; off >>= 1){
            p0 += __shfl_down(p0, off, 64);
            p1 += __shfl_down(p1, off, 64);
        }
        if (tid == 0){
            ws[WS_PART + idx*2]     = p0;
            ws[WS_PART + idx*2 + 1] = p1;
        }
    }
}

// ------- kernel 5: per-(bh,s) LN1-normalize + out1 + out2 + LN2 partials -------
__global__ __launch_bounds__(256) void kF2(const float* __restrict__ lnt_g, const float* __restrict__ lnt_b,
                   const float* __restrict__ Wse, const float* __restrict__ bse,
                   float* __restrict__ ws){
    int idx = blockIdx.x;
    int s = idx % Sc; int bh = idx / Sc; int b = bh / Hc_;
    int tid = threadIdx.x;
    __shared__ float sh_Hc[Tc*33];
    __shared__ float sh_beta[Tc];
    __shared__ float sh_o1[32];
    __shared__ float sh_mi[2];
    if (tid < 64){
        float p0 = 0.f, p1 = 0.f;
        if (tid < Sc){
            p0 = ws[WS_PART + (bh*Sc + tid)*2];
            p1 = ws[WS_PART + (bh*Sc + tid)*2 + 1];
        }
        #pragma unroll
        for (int off = 32; off; off >>= 1){
            p0 += __shfl_down(p0, off, 64);
            p1 += __shfl_down(p1, off, 64);
        }
        if (tid == 0){
            float m = p0 / (float)(Sc*Tc);
            sh_mi[0] = m;
            sh_mi[1] = rsqrtf(p1 / (float)(Sc*Tc) - m*m + EPSc);
        }
    }
    const float* h2c = ws + WS_H2 + (size_t)idx*Tc*Ec;   // contiguous [t][e]
    for (int i4 = tid; i4 < Tc*4; i4 += 256){
        int t = i4 >> 2, c4 = i4 & 3;
        float4 u = *(const float4*)(h2c + i4*4);
        float* d = sh_Hc + t*33 + c4*4;
        d[0] = u.x; d[1] = u.y; d[2] = u.z; d[3] = u.w;
    }
    for (int i4 = tid; i4 < Tc*4; i4 += 256){   // PE from table
        int t = i4 >> 2, c4 = i4 & 3;
        float4 u = *(const float4*)(ws + WS_PE + (size_t)(b*Tc + t)*PEc + c4*4);
        float* d = sh_Hc + t*33 + Ec + c4*4;
        d[0] = u.x; d[1] = u.y; d[2] = u.z; d[3] = u.w;
    }
    __syncthreads();
    float m = sh_mi[0], inv = sh_mi[1];
    if (tid < Tc){
        float bvv = ws[WS_BETA + idx*Tc + tid];
        sh_beta[tid] = (bvv - m)*inv*lnt_g[s*Tc + tid] + lnt_b[s*Tc + tid];
    }
    __syncthreads();
    if (tid < 32){
        float acc = 0.f;
        #pragma unroll 4
        for (int t = 0; t < Tc; t++) acc += sh_beta[t]*sh_Hc[t*33 + tid];
        sh_o1[tid] = lrelu(acc);
    }
    __syncthreads();
    if (tid < 64){
        float v = 0.f;
        if (tid < 16){
            float acc = bse[tid];
            const float* w = Wse + tid*32;
            #pragma unroll
            for (int d = 0; d < 32; d++) acc += sh_o1[d]*w[d];
            v = lrelu(acc);
            ws[WS_OUT2 + idx*16 + tid] = v;
        }
        float q0 = v, q1 = v*v;
        #pragma unroll
        for (int off = 32; off; off >>= 1){
            q0 += __shfl_down(q0, off, 64);
            q1 += __shfl_down(q1, off, 64);
        }
        if (tid == 0){
            ws[WS_PART2 + idx*2]     = q0;
            ws[WS_PART2 + idx*2 + 1] = q1;
        }
    }
}

// ------- kernel 6: blocks 0..31: per-(b,h) LN2 + final write; block 32: pair_sim -------
__global__ __launch_bounds__(256) void kF3s(const float* __restrict__ lns_g, const float* __restrict__ lns_b,
                    const float* __restrict__ ws, float* __restrict__ out){
    int tid = threadIdx.x;
    if (blockIdx.x == 32){
        float sq = 0.f, t2 = 0.f;
        for (int i = tid; i < Hc_*Sc*Sc; i += 256){
            float tot = 0.f;
            #pragma unroll
            for (int b = 0; b < Bc; b++){
                float v = ws[WS_ADJ + b*Hc_*Sc*Sc + i];
                sq += v*v; tot += v;
            }
            t2 += tot*tot;
        }
        __shared__ float r0[256], r1[256];
        r0[tid] = sq; r1[tid] = t2; __syncthreads();
        for (int off = 128; off; off >>= 1){
            if (tid < off){ r0[tid] += r0[tid+off]; r1[tid] += r1[tid+off]; }
            __syncthreads();
        }
        if (tid == 0)
            out[Bc*Sc*OUTc] = ((float)Bc*r0[0] - r1[0]) / 49.f / 1296.f;
        return;
    }
    int bh = blockIdx.x; int h = bh % Hc_; int b = bh / Hc_;
    __shared__ float sh_mi[2];
    if (tid < 64){
        float p0 = 0.f, p1 = 0.f;
        if (tid < Sc){
            p0 = ws[WS_PART2 + (bh*Sc + tid)*2];
            p1 = ws[WS_PART2 + (bh*Sc + tid)*2 + 1];
        }
        #pragma unroll
        for (int off = 32; off; off >>= 1){
            p0 += __shfl_down(p0, off, 64);
            p1 += __shfl_down(p1, off, 64);
        }
        if (tid == 0){
            float m = p0 / (float)(Sc*16);
            sh_mi[0] = m;
            sh_mi[1] = rsqrtf(p1 / (float)(Sc*16) - m*m + EPSc);
        }
    }
    __syncthreads();
    float m2 = sh_mi[0], inv2 = sh_mi[1];
    for (int i = tid; i < Sc*16; i += 256){
        int s = i / 16, k = i % 16;
        float v = ws[WS_OUT2 + bh*Sc*16 + i];
        out[(b*Sc + s)*OUTc + h*16 + k] = (v - m2)*inv2*lns_g[i] + lns_b[i];
    }
}

extern "C" void kernel_launch(void* const* d_in, const int* in_sizes, int n_in,
                              void* d_out, int out_size, void* d_ws, size_t ws_size,
                              hipStream_t stream){
    const float* x     = (const float*)d_in[0];
    const float* times = (const float*)d_in[1];
    const float* mask  = (const float*)d_in[2];
    const float* bn_g  = (const float*)d_in[3];
    const float* bn_b  = (const float*)d_in[4];
    const float* obs   = (const float*)d_in[5];
    const float* attn  = (const float*)d_in[6];
    const float* bidw  = (const float*)d_in[7];
    const float* projW = (const float*)d_in[8];
    const float* projb = (const float*)d_in[9];
    const float* Wq    = (const float*)d_in[10];
    const float* bq    = (const float*)d_in[11];
    const float* Wk    = (const float*)d_in[12];
    const float* bk    = (const float*)d_in[13];
    const float* Ws_   = (const float*)d_in[14];
    const float* bs_   = (const float*)d_in[15];
    const float* lnt_g = (const float*)d_in[16];
    const float* lnt_b = (const float*)d_in[17];
    const float* Wse   = (const float*)d_in[18];
    const float* bse   = (const float*)d_in[19];
    const float* lns_g = (const float*)d_in[20];
    const float* lns_b = (const float*)d_in[21];
    float* ws  = (float*)d_ws;
    float* out = (float*)d_out;

    k_layer01<<<Bc*Hc_*Tc, 256, 0, stream>>>(x, times, mask, bn_g, bn_b, obs, attn, bidw, projW, projb, ws);
    k_adjpart<<<Bc*Hc_*24, 256, 0, stream>>>(mask, bidw, ws);
    k_prune<<<Bc*Hc_*24, 256, 0, stream>>>(ws);
    k_layer1mp<<<Bc*Hc_*Tc, 256, 0, stream>>>(ws);
    kF1<<<Bc*Hc_*Sc, 256, 0, stream>>>(Wq, bq, Wk, bk, Ws_, bs_, ws);
    kF2<<<Bc*Hc_*Sc, 256, 0, stream>>>(lnt_g, lnt_b, Wse, bse, ws);
    kF3s<<<Bc*Hc_ + 1, 256, 0, stream>>>(lns_g, lns_b, ws, out);
}